// Round 1
// baseline (1123.078 us; speedup 1.0000x reference)
//
#include <hip/hip_runtime.h>
#include <hip/hip_bf16.h>
#include <math.h>

#define BB 4
#define LL 2048
#define DM 128
#define DI 256
#define DS 16
#define DTR 8
#define NB 6
#define KPRE 7
#define KC 8
#define NC 32       // chunks per sequence
#define CT 64       // chunk length (NC*CT == LL)
#define BL (BB*LL)  // 8192 tokens

// ---------------- pre-conv (K=7, pad 3/3) + exact GELU ----------------
__global__ void k_preconv_gelu(const float* __restrict__ x,
                               const float* __restrict__ w,
                               const float* __restrict__ bias,
                               float* __restrict__ h) {
    int tid = blockIdx.x * blockDim.x + threadIdx.x;   // BB*LL*DM
    int d = tid & (DM - 1);
    int l = (tid >> 7) & (LL - 1);
    int b = tid >> 18;
    float acc = bias[d];
#pragma unroll
    for (int k = 0; k < KPRE; ++k) {
        int pos = l + k - 3;
        float xv = (pos >= 0 && pos < LL) ? x[b * LL + pos] : 0.f;
        acc = fmaf(xv, w[d * KPRE + k], acc);
    }
    h[tid] = 0.5f * acc * (1.f + erff(acc * 0.70710678118654752f));
}

// ---------------- layernorm (one wave per token) ----------------
__global__ void k_layernorm(const float* __restrict__ h,
                            const float* __restrict__ w,
                            const float* __restrict__ b,
                            float* __restrict__ out) {
    int t = blockIdx.x;
    int lane = threadIdx.x;            // 64 threads
    float v0 = h[t * DM + lane];
    float v1 = h[t * DM + lane + 64];
    float s = v0 + v1;
#pragma unroll
    for (int off = 32; off; off >>= 1) s += __shfl_xor(s, off);
    float mean = s * (1.f / 128.f);
    float d0 = v0 - mean, d1 = v1 - mean;
    float q = d0 * d0 + d1 * d1;
#pragma unroll
    for (int off = 32; off; off >>= 1) q += __shfl_xor(q, off);
    float rstd = rsqrtf(q * (1.f / 128.f) + 1e-5f);
    out[t * DM + lane]      = d0 * rstd * w[lane]      + b[lane];
    out[t * DM + lane + 64] = d1 * rstd * w[lane + 64] + b[lane + 64];
}

// ---------------- generic f32 tiled GEMM: C[M x N] (+)= A[M x K] * W[N x K]^T ----------------
template <int N, int K, bool ACCUM>
__global__ __launch_bounds__(256) void k_gemm(const float* __restrict__ A,
                                              const float* __restrict__ W,
                                              float* __restrict__ C) {
    __shared__ float As[32][65];
    __shared__ float Ws[32][65];
    const int mBase = blockIdx.x * 64;
    const int nBase = blockIdx.y * 64;
    const int tid = threadIdx.x;
    const int tx = tid & 15;
    const int ty = tid >> 4;
    float acc[4][4] = {};
    for (int kB = 0; kB < K; kB += 32) {
#pragma unroll
        for (int i = 0; i < 2; ++i) {
            int idx = tid * 2 + i;        // 0..511
            int m  = idx >> 3;            // row within tile
            int kf = idx & 7;             // float4 index within 32-k
            float4 a4 = *(const float4*)(&A[(size_t)(mBase + m) * K + kB + kf * 4]);
            As[kf * 4 + 0][m] = a4.x; As[kf * 4 + 1][m] = a4.y;
            As[kf * 4 + 2][m] = a4.z; As[kf * 4 + 3][m] = a4.w;
            float4 w4 = *(const float4*)(&W[(size_t)(nBase + m) * K + kB + kf * 4]);
            Ws[kf * 4 + 0][m] = w4.x; Ws[kf * 4 + 1][m] = w4.y;
            Ws[kf * 4 + 2][m] = w4.z; Ws[kf * 4 + 3][m] = w4.w;
        }
        __syncthreads();
#pragma unroll
        for (int k = 0; k < 32; ++k) {
            float av[4], bv[4];
#pragma unroll
            for (int i = 0; i < 4; ++i) av[i] = As[k][ty * 4 + i];
#pragma unroll
            for (int j = 0; j < 4; ++j) bv[j] = Ws[k][tx * 4 + j];
#pragma unroll
            for (int i = 0; i < 4; ++i)
#pragma unroll
                for (int j = 0; j < 4; ++j)
                    acc[i][j] = fmaf(av[i], bv[j], acc[i][j]);
        }
        __syncthreads();
    }
#pragma unroll
    for (int i = 0; i < 4; ++i)
#pragma unroll
        for (int j = 0; j < 4; ++j) {
            size_t off = (size_t)(mBase + ty * 4 + i) * N + nBase + tx * 4 + j;
            if (ACCUM) C[off] += acc[i][j];
            else       C[off] = acc[i][j];
        }
}

// ---------------- causal depthwise conv (K=8) + SiLU ----------------
__global__ void k_conv_silu(const float* __restrict__ xz,
                            const float* __restrict__ cw,
                            const float* __restrict__ cb,
                            float* __restrict__ xc) {
    int tid = blockIdx.x * blockDim.x + threadIdx.x;   // BB*LL*DI
    int e = tid & (DI - 1);
    int l = (tid >> 8) & (LL - 1);
    int b = tid >> 19;
    float acc = cb[e];
#pragma unroll
    for (int k = 0; k < KC; ++k) {
        int pos = l + k - (KC - 1);
        float v = (pos >= 0) ? xz[((size_t)(b * LL + pos) << 9) + e] : 0.f;
        acc = fmaf(v, cw[e * KC + k], acc);
    }
    xc[tid] = acc / (1.f + __expf(-acc));
}

// ---------------- per-token W_x projection + delta = softplus(dt@W_dt + b_dt) ----------------
__global__ __launch_bounds__(256) void k_wx_delta(const float* __restrict__ xc,
                                                  const float* __restrict__ Wx,
                                                  const float* __restrict__ Wdt,
                                                  const float* __restrict__ bdt,
                                                  float* __restrict__ BC,
                                                  float* __restrict__ delta) {
    __shared__ float xr[DI];
    __shared__ float dbl[40];
    int t = blockIdx.x;
    int tid = threadIdx.x;
    xr[tid] = xc[(size_t)t * DI + tid];
    __syncthreads();
    if (tid < 40) {
        const float* wrow = &Wx[tid * DI];
        float s = 0.f;
        for (int k = 0; k < DI; ++k) s = fmaf(xr[k], wrow[k], s);
        dbl[tid] = s;
        if (tid >= 8) BC[(size_t)t * 32 + (tid - 8)] = s;   // Bm then Cm
    }
    __syncthreads();
    float s = bdt[tid];
#pragma unroll
    for (int r = 0; r < 8; ++r) s = fmaf(dbl[r], Wdt[tid * 8 + r], s);
    // stable softplus = max(s,0) + log1p(exp(-|s|))
    delta[(size_t)t * DI + tid] = fmaxf(s, 0.f) + log1pf(__expf(-fabsf(s)));
}

// ---------------- scan phase 1: per-chunk decay product + local end state ----------------
__global__ __launch_bounds__(256) void k_scan1(const float* __restrict__ delta,
                                               const float* __restrict__ xc,
                                               const float* __restrict__ BC,
                                               const float* __restrict__ A_log,
                                               float* __restrict__ P,
                                               float* __restrict__ hend) {
    int blk = blockIdx.x;              // BB*NC*16
    int eg = blk & 15;
    int c = (blk >> 4) & 31;
    int b = blk >> 9;
    int tid = threadIdx.x;
    int e = eg * 16 + (tid >> 4);
    int n = tid & 15;
    float Aen = -__expf(A_log[e * DS + n]);
    float h = 0.f, Pl = 1.f;
    int base = b * LL + c * CT;
    for (int l = 0; l < CT; ++l) {
        int row = base + l;
        float d = delta[(size_t)row * DI + e];
        float u = xc[(size_t)row * DI + e];
        float bm = BC[(size_t)row * 32 + n];
        float a = __expf(d * Aen);
        h = fmaf(h, a, d * u * bm);
        Pl *= a;
    }
    size_t oidx = (((size_t)(b * NC + c)) * DI + e) * DS + n;
    P[oidx] = Pl;
    hend[oidx] = h;
}

// ---------------- scan phase 2: sequential carry over 32 chunks ----------------
__global__ void k_scan_carry(const float* __restrict__ P,
                             const float* __restrict__ hend,
                             float* __restrict__ hin) {
    int tid = blockIdx.x * blockDim.x + threadIdx.x;   // BB*DI*DS = 16384
    int n = tid & 15;
    int e = (tid >> 4) & 255;
    int b = tid >> 12;
    float carry = 0.f;
    for (int c = 0; c < NC; ++c) {
        size_t idx = (((size_t)(b * NC + c)) * DI + e) * DS + n;
        hin[idx] = carry;
        carry = fmaf(P[idx], carry, hend[idx]);
    }
}

// ---------------- scan phase 3: full scan with correct incoming state, emit y ----------------
__global__ __launch_bounds__(256) void k_scan3(const float* __restrict__ delta,
                                               const float* __restrict__ xc,
                                               const float* __restrict__ BC,
                                               const float* __restrict__ A_log,
                                               const float* __restrict__ hin,
                                               float* __restrict__ y) {
    int blk = blockIdx.x;
    int eg = blk & 15;
    int c = (blk >> 4) & 31;
    int b = blk >> 9;
    int tid = threadIdx.x;
    int e = eg * 16 + (tid >> 4);
    int n = tid & 15;
    float Aen = -__expf(A_log[e * DS + n]);
    float h = hin[(((size_t)(b * NC + c)) * DI + e) * DS + n];
    int base = b * LL + c * CT;
    for (int l = 0; l < CT; ++l) {
        int row = base + l;
        float d = delta[(size_t)row * DI + e];
        float u = xc[(size_t)row * DI + e];
        float bm = BC[(size_t)row * 32 + n];
        float cm = BC[(size_t)row * 32 + 16 + n];
        float a = __expf(d * Aen);
        h = fmaf(h, a, d * u * bm);
        float yc = h * cm;
        yc += __shfl_xor(yc, 1);
        yc += __shfl_xor(yc, 2);
        yc += __shfl_xor(yc, 4);
        yc += __shfl_xor(yc, 8);
        if (n == 0) y[(size_t)row * DI + e] = yc;
    }
}

// ---------------- gating: y = (y + D_skip*xc) * silu(z) ----------------
__global__ void k_gate(const float* __restrict__ xz,
                       const float* __restrict__ xc,
                       const float* __restrict__ Dsk,
                       float* __restrict__ y) {
    int tid = blockIdx.x * blockDim.x + threadIdx.x;   // BL*DI
    int e = tid & (DI - 1);
    int t = tid >> 8;
    float z = xz[((size_t)t << 9) + DI + e];
    float val = (y[tid] + Dsk[e] * xc[tid]) * (z / (1.f + __expf(-z)));
    y[tid] = val;
}

// ---------------- final projection: out[t] = h[t,:] . out_w + out_b ----------------
__global__ void k_out(const float* __restrict__ h,
                      const float* __restrict__ ow,
                      const float* __restrict__ ob,
                      float* __restrict__ out) {
    int t = blockIdx.x;
    int lane = threadIdx.x;            // 64
    float s = h[t * DM + lane] * ow[lane] + h[t * DM + lane + 64] * ow[lane + 64];
#pragma unroll
    for (int off = 32; off; off >>= 1) s += __shfl_xor(s, off);
    if (lane == 0) out[t] = s + ob[0];
}

extern "C" void kernel_launch(void* const* d_in, const int* in_sizes, int n_in,
                              void* d_out, int out_size, void* d_ws, size_t ws_size,
                              hipStream_t stream) {
    (void)in_sizes; (void)n_in; (void)out_size; (void)ws_size;
    const float* x      = (const float*)d_in[0];
    const float* pcw    = (const float*)d_in[1];
    const float* pcb    = (const float*)d_in[2];
    const float* ln_w   = (const float*)d_in[3];
    const float* ln_b   = (const float*)d_in[4];
    const float* W_in   = (const float*)d_in[5];
    const float* conv_w = (const float*)d_in[6];
    const float* conv_b = (const float*)d_in[7];
    const float* W_x    = (const float*)d_in[8];
    const float* W_dt   = (const float*)d_in[9];
    const float* b_dt   = (const float*)d_in[10];
    const float* A_log  = (const float*)d_in[11];
    const float* D_skip = (const float*)d_in[12];
    const float* W_out  = (const float*)d_in[13];
    const float* out_w  = (const float*)d_in[14];
    const float* out_b  = (const float*)d_in[15];

    float* ws    = (float*)d_ws;
    float* h     = ws;                              // BL*DM
    float* ln    = h     + (size_t)BL * DM;         // BL*DM
    float* xz    = ln    + (size_t)BL * DM;         // BL*512
    float* xc    = xz    + (size_t)BL * 2 * DI;     // BL*256
    float* BC    = xc    + (size_t)BL * DI;         // BL*32
    float* delta = BC    + (size_t)BL * 2 * DS;     // BL*256
    float* y     = delta + (size_t)BL * DI;         // BL*256
    float* P     = y     + (size_t)BL * DI;         // B*NC*DI*DS
    float* hend  = P     + (size_t)BB * NC * DI * DS;
    float* hin   = hend  + (size_t)BB * NC * DI * DS;

    k_preconv_gelu<<<(BB * LL * DM) / 256, 256, 0, stream>>>(x, pcw, pcb, h);

    for (int blk = 0; blk < NB; ++blk) {
        k_layernorm<<<BL, 64, 0, stream>>>(h, ln_w + blk * DM, ln_b + blk * DM, ln);
        k_gemm<2 * DI, DM, false><<<dim3(BL / 64, (2 * DI) / 64), 256, 0, stream>>>(
            ln, W_in + (size_t)blk * 2 * DI * DM, xz);
        k_conv_silu<<<(BL * DI) / 256, 256, 0, stream>>>(
            xz, conv_w + (size_t)blk * DI * KC, conv_b + blk * DI, xc);
        k_wx_delta<<<BL, 256, 0, stream>>>(
            xc, W_x + (size_t)blk * 40 * DI, W_dt + (size_t)blk * DI * DTR,
            b_dt + blk * DI, BC, delta);
        k_scan1<<<BB * NC * (DI / 16), 256, 0, stream>>>(
            delta, xc, BC, A_log + (size_t)blk * DI * DS, P, hend);
        k_scan_carry<<<(BB * DI * DS) / 256, 256, 0, stream>>>(P, hend, hin);
        k_scan3<<<BB * NC * (DI / 16), 256, 0, stream>>>(
            delta, xc, BC, A_log + (size_t)blk * DI * DS, hin, y);
        k_gate<<<BL, 256, 0, stream>>>(xz, xc, D_skip + blk * DI, y);
        k_gemm<DM, DI, true><<<dim3(BL / 64, DM / 64), 256, 0, stream>>>(
            y, W_out + (size_t)blk * DM * DI, h);
    }

    k_out<<<BL, 64, 0, stream>>>(h, out_w, out_b, (float*)d_out);
}

// Round 2
// 1078.403 us; speedup vs baseline: 1.0414x; 1.0414x over previous
//
#include <hip/hip_runtime.h>
#include <hip/hip_bf16.h>
#include <math.h>

#define BB 4
#define LL 2048
#define DM 128
#define DI 256
#define DS 16
#define DTR 8
#define NB 6
#define KPRE 7
#define KC 8
#define NC 32       // chunks per sequence
#define CT 64       // chunk length (NC*CT == LL)
#define BL (BB*LL)  // 8192 tokens

// ---------------- pre-conv (K=7, pad 3/3) + exact GELU ----------------
__global__ void k_preconv_gelu(const float* __restrict__ x,
                               const float* __restrict__ w,
                               const float* __restrict__ bias,
                               float* __restrict__ h) {
    int tid = blockIdx.x * blockDim.x + threadIdx.x;   // BB*LL*DM
    int d = tid & (DM - 1);
    int l = (tid >> 7) & (LL - 1);
    int b = tid >> 18;
    float acc = bias[d];
#pragma unroll
    for (int k = 0; k < KPRE; ++k) {
        int pos = l + k - 3;
        float xv = (pos >= 0 && pos < LL) ? x[b * LL + pos] : 0.f;
        acc = fmaf(xv, w[d * KPRE + k], acc);
    }
    h[tid] = 0.5f * acc * (1.f + erff(acc * 0.70710678118654752f));
}

// ---------------- layernorm (one wave per token, 4 tokens/block) ----------------
__global__ __launch_bounds__(256) void k_layernorm(const float* __restrict__ h,
                            const float* __restrict__ w,
                            const float* __restrict__ b,
                            float* __restrict__ out) {
    int t = blockIdx.x * 4 + (threadIdx.x >> 6);
    int lane = threadIdx.x & 63;
    float v0 = h[t * DM + lane];
    float v1 = h[t * DM + lane + 64];
    float s = v0 + v1;
#pragma unroll
    for (int off = 32; off; off >>= 1) s += __shfl_xor(s, off);
    float mean = s * (1.f / 128.f);
    float d0 = v0 - mean, d1 = v1 - mean;
    float q = d0 * d0 + d1 * d1;
#pragma unroll
    for (int off = 32; off; off >>= 1) q += __shfl_xor(q, off);
    float rstd = rsqrtf(q * (1.f / 128.f) + 1e-5f);
    out[t * DM + lane]      = d0 * rstd * w[lane]      + b[lane];
    out[t * DM + lane + 64] = d1 * rstd * w[lane + 64] + b[lane + 64];
}

// ---------------- generic f32 tiled GEMM: C[M x N] (+)= A[M x K] * W[N x K]^T ----------------
template <int N, int K, bool ACCUM>
__global__ __launch_bounds__(256) void k_gemm(const float* __restrict__ A,
                                              const float* __restrict__ W,
                                              float* __restrict__ C) {
    __shared__ float As[32][65];
    __shared__ float Ws[32][65];
    const int mBase = blockIdx.x * 64;
    const int nBase = blockIdx.y * 64;
    const int tid = threadIdx.x;
    const int tx = tid & 15;
    const int ty = tid >> 4;
    float acc[4][4] = {};
    for (int kB = 0; kB < K; kB += 32) {
#pragma unroll
        for (int i = 0; i < 2; ++i) {
            int idx = tid * 2 + i;        // 0..511
            int m  = idx >> 3;            // row within tile
            int kf = idx & 7;             // float4 index within 32-k
            float4 a4 = *(const float4*)(&A[(size_t)(mBase + m) * K + kB + kf * 4]);
            As[kf * 4 + 0][m] = a4.x; As[kf * 4 + 1][m] = a4.y;
            As[kf * 4 + 2][m] = a4.z; As[kf * 4 + 3][m] = a4.w;
            float4 w4 = *(const float4*)(&W[(size_t)(nBase + m) * K + kB + kf * 4]);
            Ws[kf * 4 + 0][m] = w4.x; Ws[kf * 4 + 1][m] = w4.y;
            Ws[kf * 4 + 2][m] = w4.z; Ws[kf * 4 + 3][m] = w4.w;
        }
        __syncthreads();
#pragma unroll
        for (int k = 0; k < 32; ++k) {
            float av[4], bv[4];
#pragma unroll
            for (int i = 0; i < 4; ++i) av[i] = As[k][ty * 4 + i];
#pragma unroll
            for (int j = 0; j < 4; ++j) bv[j] = Ws[k][tx * 4 + j];
#pragma unroll
            for (int i = 0; i < 4; ++i)
#pragma unroll
                for (int j = 0; j < 4; ++j)
                    acc[i][j] = fmaf(av[i], bv[j], acc[i][j]);
        }
        __syncthreads();
    }
#pragma unroll
    for (int i = 0; i < 4; ++i)
#pragma unroll
        for (int j = 0; j < 4; ++j) {
            size_t off = (size_t)(mBase + ty * 4 + i) * N + nBase + tx * 4 + j;
            if (ACCUM) C[off] += acc[i][j];
            else       C[off] = acc[i][j];
        }
}

// ---------------- causal depthwise conv (K=8) + SiLU ----------------
__global__ void k_conv_silu(const float* __restrict__ xz,
                            const float* __restrict__ cw,
                            const float* __restrict__ cb,
                            float* __restrict__ xc) {
    int tid = blockIdx.x * blockDim.x + threadIdx.x;   // BB*LL*DI
    int e = tid & (DI - 1);
    int l = (tid >> 8) & (LL - 1);
    int b = tid >> 19;
    float acc = cb[e];
#pragma unroll
    for (int k = 0; k < KC; ++k) {
        int pos = l + k - (KC - 1);
        float v = (pos >= 0) ? xz[((size_t)(b * LL + pos) << 9) + e] : 0.f;
        acc = fmaf(v, cw[e * KC + k], acc);
    }
    xc[tid] = acc / (1.f + __expf(-acc));
}

// ---------------- wave-parallel W_x projection + delta = softplus(dt@W_dt + b_dt) ----------------
// One 64-lane wave per token; 4 tokens per 256-thread block.
__global__ __launch_bounds__(256) void k_wx_delta(const float* __restrict__ xc,
                                                  const float* __restrict__ Wx,
                                                  const float* __restrict__ Wdt,
                                                  const float* __restrict__ bdt,
                                                  float* __restrict__ BC,
                                                  float* __restrict__ delta) {
    int lane = threadIdx.x & 63;
    int t = blockIdx.x * 4 + (threadIdx.x >> 6);
    const float* xr = &xc[(size_t)t * DI];
    float x0 = xr[lane], x1 = xr[lane + 64], x2 = xr[lane + 128], x3 = xr[lane + 192];
    float dt[8];
    float bcv = 0.f;
#pragma unroll
    for (int o = 0; o < 40; ++o) {
        const float* w = &Wx[o * DI];
        float s = x0 * w[lane];
        s = fmaf(x1, w[lane + 64], s);
        s = fmaf(x2, w[lane + 128], s);
        s = fmaf(x3, w[lane + 192], s);
#pragma unroll
        for (int off = 32; off; off >>= 1) s += __shfl_xor(s, off);
        if (o < 8) dt[o] = s;
        else if (lane == o - 8) bcv = s;
    }
    if (lane < 32) BC[(size_t)t * 32 + lane] = bcv;
#pragma unroll
    for (int j = 0; j < 4; ++j) {
        int e = lane + 64 * j;
        float s = bdt[e];
#pragma unroll
        for (int r = 0; r < 8; ++r) s = fmaf(dt[r], Wdt[e * 8 + r], s);
        // stable softplus
        delta[(size_t)t * DI + e] = fmaxf(s, 0.f) + log1pf(__expf(-fabsf(s)));
    }
}

// ---------------- scan phase 1: per-chunk decay product + local end state ----------------
__global__ __launch_bounds__(256) void k_scan1(const float* __restrict__ delta,
                                               const float* __restrict__ xc,
                                               const float* __restrict__ BC,
                                               const float* __restrict__ A_log,
                                               float* __restrict__ P,
                                               float* __restrict__ hend) {
    int blk = blockIdx.x;              // BB*NC*16
    int eg = blk & 15;
    int c = (blk >> 4) & 31;
    int b = blk >> 9;
    int tid = threadIdx.x;
    int e = eg * 16 + (tid >> 4);
    int n = tid & 15;
    float Aen = -__expf(A_log[e * DS + n]);
    float h = 0.f, Pl = 1.f;
    int base = b * LL + c * CT;
    for (int l = 0; l < CT; ++l) {
        int row = base + l;
        float d = delta[(size_t)row * DI + e];
        float u = xc[(size_t)row * DI + e];
        float bm = BC[(size_t)row * 32 + n];
        float a = __expf(d * Aen);
        h = fmaf(h, a, d * u * bm);
        Pl *= a;
    }
    size_t oidx = (((size_t)(b * NC + c)) * DI + e) * DS + n;
    P[oidx] = Pl;
    hend[oidx] = h;
}

// ---------------- scan phase 2: sequential carry over 32 chunks ----------------
__global__ void k_scan_carry(const float* __restrict__ P,
                             const float* __restrict__ hend,
                             float* __restrict__ hin) {
    int tid = blockIdx.x * blockDim.x + threadIdx.x;   // BB*DI*DS = 16384
    int n = tid & 15;
    int e = (tid >> 4) & 255;
    int b = tid >> 12;
    float carry = 0.f;
    for (int c = 0; c < NC; ++c) {
        size_t idx = (((size_t)(b * NC + c)) * DI + e) * DS + n;
        hin[idx] = carry;
        carry = fmaf(P[idx], carry, hend[idx]);
    }
}

// ---------------- scan phase 3: full scan + fused gating ----------------
// y[row,e] = (sum_n h*Cm + D_skip[e]*u) * silu(z[row,e])
__global__ __launch_bounds__(256) void k_scan3(const float* __restrict__ delta,
                                               const float* __restrict__ xc,
                                               const float* __restrict__ BC,
                                               const float* __restrict__ A_log,
                                               const float* __restrict__ hin,
                                               const float* __restrict__ xz,
                                               const float* __restrict__ Dsk,
                                               float* __restrict__ y) {
    int blk = blockIdx.x;
    int eg = blk & 15;
    int c = (blk >> 4) & 31;
    int b = blk >> 9;
    int tid = threadIdx.x;
    int e = eg * 16 + (tid >> 4);
    int n = tid & 15;
    float Aen = -__expf(A_log[e * DS + n]);
    float dsk = Dsk[e];
    float h = hin[(((size_t)(b * NC + c)) * DI + e) * DS + n];
    int base = b * LL + c * CT;
    for (int l = 0; l < CT; ++l) {
        int row = base + l;
        float d = delta[(size_t)row * DI + e];
        float u = xc[(size_t)row * DI + e];
        float bm = BC[(size_t)row * 32 + n];
        float cm = BC[(size_t)row * 32 + 16 + n];
        float a = __expf(d * Aen);
        h = fmaf(h, a, d * u * bm);
        float yc = h * cm;
        yc += __shfl_xor(yc, 1);
        yc += __shfl_xor(yc, 2);
        yc += __shfl_xor(yc, 4);
        yc += __shfl_xor(yc, 8);
        if (n == 0) {
            float z = xz[((size_t)row << 9) + DI + e];
            float val = (yc + dsk * u) * (z / (1.f + __expf(-z)));
            y[(size_t)row * DI + e] = val;
        }
    }
}

// ---------------- final projection: out[t] = h[t,:] . out_w + out_b ----------------
__global__ void k_out(const float* __restrict__ h,
                      const float* __restrict__ ow,
                      const float* __restrict__ ob,
                      float* __restrict__ out) {
    int t = blockIdx.x * 4 + (threadIdx.x >> 6);
    int lane = threadIdx.x & 63;
    float s = h[t * DM + lane] * ow[lane] + h[t * DM + lane + 64] * ow[lane + 64];
#pragma unroll
    for (int off = 32; off; off >>= 1) s += __shfl_xor(s, off);
    if (lane == 0) out[t] = s + ob[0];
}

extern "C" void kernel_launch(void* const* d_in, const int* in_sizes, int n_in,
                              void* d_out, int out_size, void* d_ws, size_t ws_size,
                              hipStream_t stream) {
    (void)in_sizes; (void)n_in; (void)out_size; (void)ws_size;
    const float* x      = (const float*)d_in[0];
    const float* pcw    = (const float*)d_in[1];
    const float* pcb    = (const float*)d_in[2];
    const float* ln_w   = (const float*)d_in[3];
    const float* ln_b   = (const float*)d_in[4];
    const float* W_in   = (const float*)d_in[5];
    const float* conv_w = (const float*)d_in[6];
    const float* conv_b = (const float*)d_in[7];
    const float* W_x    = (const float*)d_in[8];
    const float* W_dt   = (const float*)d_in[9];
    const float* b_dt   = (const float*)d_in[10];
    const float* A_log  = (const float*)d_in[11];
    const float* D_skip = (const float*)d_in[12];
    const float* W_out  = (const float*)d_in[13];
    const float* out_w  = (const float*)d_in[14];
    const float* out_b  = (const float*)d_in[15];

    float* ws    = (float*)d_ws;
    float* h     = ws;                              // BL*DM
    float* ln    = h     + (size_t)BL * DM;         // BL*DM
    float* xz    = ln    + (size_t)BL * DM;         // BL*512
    float* xc    = xz    + (size_t)BL * 2 * DI;     // BL*256
    float* BC    = xc    + (size_t)BL * DI;         // BL*32
    float* delta = BC    + (size_t)BL * 2 * DS;     // BL*256
    float* y     = delta + (size_t)BL * DI;         // BL*256
    float* P     = y     + (size_t)BL * DI;         // B*NC*DI*DS
    float* hend  = P     + (size_t)BB * NC * DI * DS;
    float* hin   = hend  + (size_t)BB * NC * DI * DS;

    k_preconv_gelu<<<(BB * LL * DM) / 256, 256, 0, stream>>>(x, pcw, pcb, h);

    for (int blk = 0; blk < NB; ++blk) {
        k_layernorm<<<BL / 4, 256, 0, stream>>>(h, ln_w + blk * DM, ln_b + blk * DM, ln);
        k_gemm<2 * DI, DM, false><<<dim3(BL / 64, (2 * DI) / 64), 256, 0, stream>>>(
            ln, W_in + (size_t)blk * 2 * DI * DM, xz);
        k_conv_silu<<<(BL * DI) / 256, 256, 0, stream>>>(
            xz, conv_w + (size_t)blk * DI * KC, conv_b + blk * DI, xc);
        k_wx_delta<<<BL / 4, 256, 0, stream>>>(
            xc, W_x + (size_t)blk * 40 * DI, W_dt + (size_t)blk * DI * DTR,
            b_dt + blk * DI, BC, delta);
        k_scan1<<<BB * NC * (DI / 16), 256, 0, stream>>>(
            delta, xc, BC, A_log + (size_t)blk * DI * DS, P, hend);
        k_scan_carry<<<(BB * DI * DS) / 256, 256, 0, stream>>>(P, hend, hin);
        k_scan3<<<BB * NC * (DI / 16), 256, 0, stream>>>(
            delta, xc, BC, A_log + (size_t)blk * DI * DS, hin, xz,
            D_skip + blk * DI, y);
        k_gemm<DM, DI, true><<<dim3(BL / 64, DM / 64), 256, 0, stream>>>(
            y, W_out + (size_t)blk * DM * DI, h);
    }

    k_out<<<BL / 4, 256, 0, stream>>>(h, out_w, out_b, (float*)d_out);
}

// Round 3
// 966.917 us; speedup vs baseline: 1.1615x; 1.1153x over previous
//
#include <hip/hip_runtime.h>
#include <hip/hip_bf16.h>
#include <math.h>

#define BB 4
#define LL 2048
#define DM 128
#define DI 256
#define DS 16
#define DTR 8
#define NB 6
#define KPRE 7
#define KC 8
#define NC 32       // chunks per sequence
#define CT 64       // chunk length (NC*CT == LL)
#define BL (BB*LL)  // 8192 tokens
#define SU 8        // scan unroll factor

// ---------------- pre-conv (K=7, pad 3/3) + exact GELU ----------------
__global__ void k_preconv_gelu(const float* __restrict__ x,
                               const float* __restrict__ w,
                               const float* __restrict__ bias,
                               float* __restrict__ h) {
    int tid = blockIdx.x * blockDim.x + threadIdx.x;   // BB*LL*DM
    int d = tid & (DM - 1);
    int l = (tid >> 7) & (LL - 1);
    int b = tid >> 18;
    float acc = bias[d];
#pragma unroll
    for (int k = 0; k < KPRE; ++k) {
        int pos = l + k - 3;
        float xv = (pos >= 0 && pos < LL) ? x[b * LL + pos] : 0.f;
        acc = fmaf(xv, w[d * KPRE + k], acc);
    }
    h[tid] = 0.5f * acc * (1.f + erff(acc * 0.70710678118654752f));
}

// ---------------- layernorm (one wave per token, 4 tokens/block) ----------------
__global__ __launch_bounds__(256) void k_layernorm(const float* __restrict__ h,
                            const float* __restrict__ w,
                            const float* __restrict__ b,
                            float* __restrict__ out) {
    int t = blockIdx.x * 4 + (threadIdx.x >> 6);
    int lane = threadIdx.x & 63;
    float v0 = h[t * DM + lane];
    float v1 = h[t * DM + lane + 64];
    float s = v0 + v1;
#pragma unroll
    for (int off = 32; off; off >>= 1) s += __shfl_xor(s, off);
    float mean = s * (1.f / 128.f);
    float d0 = v0 - mean, d1 = v1 - mean;
    float q = d0 * d0 + d1 * d1;
#pragma unroll
    for (int off = 32; off; off >>= 1) q += __shfl_xor(q, off);
    float rstd = rsqrtf(q * (1.f / 128.f) + 1e-5f);
    out[t * DM + lane]      = d0 * rstd * w[lane]      + b[lane];
    out[t * DM + lane + 64] = d1 * rstd * w[lane + 64] + b[lane + 64];
}

// ---------------- generic f32 tiled GEMM: C[M x N] (+)= A[M x K] * W[N x K]^T ----------------
template <int N, int K, bool ACCUM>
__global__ __launch_bounds__(256) void k_gemm(const float* __restrict__ A,
                                              const float* __restrict__ W,
                                              float* __restrict__ C) {
    __shared__ float As[32][65];
    __shared__ float Ws[32][65];
    const int mBase = blockIdx.x * 64;
    const int nBase = blockIdx.y * 64;
    const int tid = threadIdx.x;
    const int tx = tid & 15;
    const int ty = tid >> 4;
    float acc[4][4] = {};
    for (int kB = 0; kB < K; kB += 32) {
#pragma unroll
        for (int i = 0; i < 2; ++i) {
            int idx = tid * 2 + i;        // 0..511
            int m  = idx >> 3;            // row within tile
            int kf = idx & 7;             // float4 index within 32-k
            float4 a4 = *(const float4*)(&A[(size_t)(mBase + m) * K + kB + kf * 4]);
            As[kf * 4 + 0][m] = a4.x; As[kf * 4 + 1][m] = a4.y;
            As[kf * 4 + 2][m] = a4.z; As[kf * 4 + 3][m] = a4.w;
            float4 w4 = *(const float4*)(&W[(size_t)(nBase + m) * K + kB + kf * 4]);
            Ws[kf * 4 + 0][m] = w4.x; Ws[kf * 4 + 1][m] = w4.y;
            Ws[kf * 4 + 2][m] = w4.z; Ws[kf * 4 + 3][m] = w4.w;
        }
        __syncthreads();
#pragma unroll
        for (int k = 0; k < 32; ++k) {
            float av[4], bv[4];
#pragma unroll
            for (int i = 0; i < 4; ++i) av[i] = As[k][ty * 4 + i];
#pragma unroll
            for (int j = 0; j < 4; ++j) bv[j] = Ws[k][tx * 4 + j];
#pragma unroll
            for (int i = 0; i < 4; ++i)
#pragma unroll
                for (int j = 0; j < 4; ++j)
                    acc[i][j] = fmaf(av[i], bv[j], acc[i][j]);
        }
        __syncthreads();
    }
#pragma unroll
    for (int i = 0; i < 4; ++i)
#pragma unroll
        for (int j = 0; j < 4; ++j) {
            size_t off = (size_t)(mBase + ty * 4 + i) * N + nBase + tx * 4 + j;
            if (ACCUM) C[off] += acc[i][j];
            else       C[off] = acc[i][j];
        }
}

// ---------------- causal depthwise conv (K=8) + SiLU ----------------
__global__ void k_conv_silu(const float* __restrict__ xz,
                            const float* __restrict__ cw,
                            const float* __restrict__ cb,
                            float* __restrict__ xc) {
    int tid = blockIdx.x * blockDim.x + threadIdx.x;   // BB*LL*DI
    int e = tid & (DI - 1);
    int l = (tid >> 8) & (LL - 1);
    int b = tid >> 19;
    float acc = cb[e];
#pragma unroll
    for (int k = 0; k < KC; ++k) {
        int pos = l + k - (KC - 1);
        float v = (pos >= 0) ? xz[((size_t)(b * LL + pos) << 9) + e] : 0.f;
        acc = fmaf(v, cw[e * KC + k], acc);
    }
    xc[tid] = acc / (1.f + __expf(-acc));
}

// ---------------- wave-parallel W_x projection + delta = softplus(dt@W_dt + b_dt) ----------------
__global__ __launch_bounds__(256) void k_wx_delta(const float* __restrict__ xc,
                                                  const float* __restrict__ Wx,
                                                  const float* __restrict__ Wdt,
                                                  const float* __restrict__ bdt,
                                                  float* __restrict__ BC,
                                                  float* __restrict__ delta) {
    int lane = threadIdx.x & 63;
    int t = blockIdx.x * 4 + (threadIdx.x >> 6);
    const float* xr = &xc[(size_t)t * DI];
    float x0 = xr[lane], x1 = xr[lane + 64], x2 = xr[lane + 128], x3 = xr[lane + 192];
    float dt[8];
    float bcv = 0.f;
#pragma unroll
    for (int o = 0; o < 40; ++o) {
        const float* w = &Wx[o * DI];
        float s = x0 * w[lane];
        s = fmaf(x1, w[lane + 64], s);
        s = fmaf(x2, w[lane + 128], s);
        s = fmaf(x3, w[lane + 192], s);
#pragma unroll
        for (int off = 32; off; off >>= 1) s += __shfl_xor(s, off);
        if (o < 8) dt[o] = s;
        else if (lane == o - 8) bcv = s;
    }
    if (lane < 32) BC[(size_t)t * 32 + lane] = bcv;
#pragma unroll
    for (int j = 0; j < 4; ++j) {
        int e = lane + 64 * j;
        float s = bdt[e];
#pragma unroll
        for (int r = 0; r < 8; ++r) s = fmaf(dt[r], Wdt[e * 8 + r], s);
        delta[(size_t)t * DI + e] = fmaxf(s, 0.f) + log1pf(__expf(-fabsf(s)));
    }
}

// ---------------- scan phase 1: per-chunk decay product + local end state ----------------
// Unrolled by SU: batch independent loads + exps ahead of the serial h-chain.
__global__ __launch_bounds__(256) void k_scan1(const float* __restrict__ delta,
                                               const float* __restrict__ xc,
                                               const float* __restrict__ BC,
                                               const float* __restrict__ A_log,
                                               float* __restrict__ P,
                                               float* __restrict__ hend) {
    int blk = blockIdx.x;              // BB*NC*16
    int eg = blk & 15;
    int c = (blk >> 4) & 31;
    int b = blk >> 9;
    int tid = threadIdx.x;
    int e = eg * 16 + (tid >> 4);
    int n = tid & 15;
    float Aen = -__expf(A_log[e * DS + n]);
    float h = 0.f, Pl = 1.f;
    int base = b * LL + c * CT;
    for (int l0 = 0; l0 < CT; l0 += SU) {
        float d[SU], u[SU], bm[SU];
#pragma unroll
        for (int j = 0; j < SU; ++j) {
            int row = base + l0 + j;
            d[j]  = delta[(size_t)row * DI + e];
            u[j]  = xc[(size_t)row * DI + e];
            bm[j] = BC[(size_t)row * 32 + n];
        }
        float a[SU], w[SU];
#pragma unroll
        for (int j = 0; j < SU; ++j) {
            a[j] = __expf(d[j] * Aen);
            w[j] = d[j] * u[j] * bm[j];
        }
#pragma unroll
        for (int j = 0; j < SU; ++j) {
            h = fmaf(h, a[j], w[j]);
            Pl *= a[j];
        }
    }
    size_t oidx = (((size_t)(b * NC + c)) * DI + e) * DS + n;
    P[oidx] = Pl;
    hend[oidx] = h;
}

// ---------------- scan phase 2: sequential carry over 32 chunks ----------------
__global__ void k_scan_carry(const float* __restrict__ P,
                             const float* __restrict__ hend,
                             float* __restrict__ hin) {
    int tid = blockIdx.x * blockDim.x + threadIdx.x;   // BB*DI*DS = 16384
    int n = tid & 15;
    int e = (tid >> 4) & 255;
    int b = tid >> 12;
    float carry = 0.f;
    for (int c = 0; c < NC; ++c) {
        size_t idx = (((size_t)(b * NC + c)) * DI + e) * DS + n;
        hin[idx] = carry;
        carry = fmaf(P[idx], carry, hend[idx]);
    }
}

// ---------------- scan phase 3: full scan + fused gating (unrolled by SU) ----------------
__global__ __launch_bounds__(256) void k_scan3(const float* __restrict__ delta,
                                               const float* __restrict__ xc,
                                               const float* __restrict__ BC,
                                               const float* __restrict__ A_log,
                                               const float* __restrict__ hin,
                                               const float* __restrict__ xz,
                                               const float* __restrict__ Dsk,
                                               float* __restrict__ y) {
    int blk = blockIdx.x;
    int eg = blk & 15;
    int c = (blk >> 4) & 31;
    int b = blk >> 9;
    int tid = threadIdx.x;
    int e = eg * 16 + (tid >> 4);
    int n = tid & 15;
    float Aen = -__expf(A_log[e * DS + n]);
    float dsk = Dsk[e];
    float h = hin[(((size_t)(b * NC + c)) * DI + e) * DS + n];
    int base = b * LL + c * CT;
    for (int l0 = 0; l0 < CT; l0 += SU) {
        float d[SU], u[SU], bm[SU], cm[SU], zv[SU];
#pragma unroll
        for (int j = 0; j < SU; ++j) {
            int row = base + l0 + j;
            d[j]  = delta[(size_t)row * DI + e];
            u[j]  = xc[(size_t)row * DI + e];
            bm[j] = BC[(size_t)row * 32 + n];
            cm[j] = BC[(size_t)row * 32 + 16 + n];
            zv[j] = xz[((size_t)row << 9) + DI + e];   // z (broadcast across n-lanes)
        }
        float a[SU], w[SU];
#pragma unroll
        for (int j = 0; j < SU; ++j) {
            a[j] = __expf(d[j] * Aen);
            w[j] = d[j] * u[j] * bm[j];
        }
#pragma unroll
        for (int j = 0; j < SU; ++j) {
            h = fmaf(h, a[j], w[j]);
            float yc = h * cm[j];
            yc += __shfl_xor(yc, 1);
            yc += __shfl_xor(yc, 2);
            yc += __shfl_xor(yc, 4);
            yc += __shfl_xor(yc, 8);
            if (n == 0) {
                int row = base + l0 + j;
                float z = zv[j];
                float val = (yc + dsk * u[j]) * (z / (1.f + __expf(-z)));
                y[(size_t)row * DI + e] = val;
            }
        }
    }
}

// ---------------- final projection: out[t] = h[t,:] . out_w + out_b ----------------
__global__ void k_out(const float* __restrict__ h,
                      const float* __restrict__ ow,
                      const float* __restrict__ ob,
                      float* __restrict__ out) {
    int t = blockIdx.x * 4 + (threadIdx.x >> 6);
    int lane = threadIdx.x & 63;
    float s = h[t * DM + lane] * ow[lane] + h[t * DM + lane + 64] * ow[lane + 64];
#pragma unroll
    for (int off = 32; off; off >>= 1) s += __shfl_xor(s, off);
    if (lane == 0) out[t] = s + ob[0];
}

extern "C" void kernel_launch(void* const* d_in, const int* in_sizes, int n_in,
                              void* d_out, int out_size, void* d_ws, size_t ws_size,
                              hipStream_t stream) {
    (void)in_sizes; (void)n_in; (void)out_size; (void)ws_size;
    const float* x      = (const float*)d_in[0];
    const float* pcw    = (const float*)d_in[1];
    const float* pcb    = (const float*)d_in[2];
    const float* ln_w   = (const float*)d_in[3];
    const float* ln_b   = (const float*)d_in[4];
    const float* W_in   = (const float*)d_in[5];
    const float* conv_w = (const float*)d_in[6];
    const float* conv_b = (const float*)d_in[7];
    const float* W_x    = (const float*)d_in[8];
    const float* W_dt   = (const float*)d_in[9];
    const float* b_dt   = (const float*)d_in[10];
    const float* A_log  = (const float*)d_in[11];
    const float* D_skip = (const float*)d_in[12];
    const float* W_out  = (const float*)d_in[13];
    const float* out_w  = (const float*)d_in[14];
    const float* out_b  = (const float*)d_in[15];

    float* ws    = (float*)d_ws;
    float* h     = ws;                              // BL*DM
    float* ln    = h     + (size_t)BL * DM;         // BL*DM
    float* xz    = ln    + (size_t)BL * DM;         // BL*512
    float* xc    = xz    + (size_t)BL * 2 * DI;     // BL*256
    float* BC    = xc    + (size_t)BL * DI;         // BL*32
    float* delta = BC    + (size_t)BL * 2 * DS;     // BL*256
    float* y     = delta + (size_t)BL * DI;         // BL*256
    float* P     = y     + (size_t)BL * DI;         // B*NC*DI*DS
    float* hend  = P     + (size_t)BB * NC * DI * DS;
    float* hin   = hend  + (size_t)BB * NC * DI * DS;

    k_preconv_gelu<<<(BB * LL * DM) / 256, 256, 0, stream>>>(x, pcw, pcb, h);

    for (int blk = 0; blk < NB; ++blk) {
        k_layernorm<<<BL / 4, 256, 0, stream>>>(h, ln_w + blk * DM, ln_b + blk * DM, ln);
        k_gemm<2 * DI, DM, false><<<dim3(BL / 64, (2 * DI) / 64), 256, 0, stream>>>(
            ln, W_in + (size_t)blk * 2 * DI * DM, xz);
        k_conv_silu<<<(BL * DI) / 256, 256, 0, stream>>>(
            xz, conv_w + (size_t)blk * DI * KC, conv_b + blk * DI, xc);
        k_wx_delta<<<BL / 4, 256, 0, stream>>>(
            xc, W_x + (size_t)blk * 40 * DI, W_dt + (size_t)blk * DI * DTR,
            b_dt + blk * DI, BC, delta);
        k_scan1<<<BB * NC * (DI / 16), 256, 0, stream>>>(
            delta, xc, BC, A_log + (size_t)blk * DI * DS, P, hend);
        k_scan_carry<<<(BB * DI * DS) / 256, 256, 0, stream>>>(P, hend, hin);
        k_scan3<<<BB * NC * (DI / 16), 256, 0, stream>>>(
            delta, xc, BC, A_log + (size_t)blk * DI * DS, hin, xz,
            D_skip + blk * DI, y);
        k_gemm<DM, DI, true><<<dim3(BL / 64, DM / 64), 256, 0, stream>>>(
            y, W_out + (size_t)blk * DM * DI, h);
    }

    k_out<<<BL / 4, 256, 0, stream>>>(h, out_w, out_b, (float*)d_out);
}

// Round 4
// 863.730 us; speedup vs baseline: 1.3003x; 1.1195x over previous
//
#include <hip/hip_runtime.h>
#include <hip/hip_bf16.h>
#include <math.h>

#define BB 4
#define LL 2048
#define DM 128
#define DI 256
#define DS 16
#define DTR 8
#define NB 6
#define KPRE 7
#define KC 8
#define NC 64       // chunks per sequence
#define CT 32       // chunk length (NC*CT == LL)
#define BL (BB*LL)  // 8192 tokens
#define SU 4        // scan unroll factor

// ---------------- pre-conv (K=7, pad 3/3) + exact GELU ----------------
__global__ void k_preconv_gelu(const float* __restrict__ x,
                               const float* __restrict__ w,
                               const float* __restrict__ bias,
                               float* __restrict__ h) {
    int tid = blockIdx.x * blockDim.x + threadIdx.x;   // BB*LL*DM
    int d = tid & (DM - 1);
    int l = (tid >> 7) & (LL - 1);
    int b = tid >> 18;
    float acc = bias[d];
#pragma unroll
    for (int k = 0; k < KPRE; ++k) {
        int pos = l + k - 3;
        float xv = (pos >= 0 && pos < LL) ? x[b * LL + pos] : 0.f;
        acc = fmaf(xv, w[d * KPRE + k], acc);
    }
    h[tid] = 0.5f * acc * (1.f + erff(acc * 0.70710678118654752f));
}

// ---------------- layernorm (one wave per token, 4 tokens/block) ----------------
__global__ __launch_bounds__(256) void k_layernorm(const float* __restrict__ h,
                            const float* __restrict__ w,
                            const float* __restrict__ b,
                            float* __restrict__ out) {
    int t = blockIdx.x * 4 + (threadIdx.x >> 6);
    int lane = threadIdx.x & 63;
    float v0 = h[t * DM + lane];
    float v1 = h[t * DM + lane + 64];
    float s = v0 + v1;
#pragma unroll
    for (int off = 32; off; off >>= 1) s += __shfl_xor(s, off);
    float mean = s * (1.f / 128.f);
    float d0 = v0 - mean, d1 = v1 - mean;
    float q = d0 * d0 + d1 * d1;
#pragma unroll
    for (int off = 32; off; off >>= 1) q += __shfl_xor(q, off);
    float rstd = rsqrtf(q * (1.f / 128.f) + 1e-5f);
    out[t * DM + lane]      = d0 * rstd * w[lane]      + b[lane];
    out[t * DM + lane + 64] = d1 * rstd * w[lane + 64] + b[lane + 64];
}

// ---------------- generic f32 tiled GEMM: C[M x N] (+)= A[M x K] * W[N x K]^T ----------------
template <int N, int K, bool ACCUM>
__global__ __launch_bounds__(256) void k_gemm(const float* __restrict__ A,
                                              const float* __restrict__ W,
                                              float* __restrict__ C) {
    __shared__ float As[32][65];
    __shared__ float Ws[32][65];
    const int mBase = blockIdx.x * 64;
    const int nBase = blockIdx.y * 64;
    const int tid = threadIdx.x;
    const int tx = tid & 15;
    const int ty = tid >> 4;
    float acc[4][4] = {};
    for (int kB = 0; kB < K; kB += 32) {
#pragma unroll
        for (int i = 0; i < 2; ++i) {
            int idx = tid * 2 + i;        // 0..511
            int m  = idx >> 3;            // row within tile
            int kf = idx & 7;             // float4 index within 32-k
            float4 a4 = *(const float4*)(&A[(size_t)(mBase + m) * K + kB + kf * 4]);
            As[kf * 4 + 0][m] = a4.x; As[kf * 4 + 1][m] = a4.y;
            As[kf * 4 + 2][m] = a4.z; As[kf * 4 + 3][m] = a4.w;
            float4 w4 = *(const float4*)(&W[(size_t)(nBase + m) * K + kB + kf * 4]);
            Ws[kf * 4 + 0][m] = w4.x; Ws[kf * 4 + 1][m] = w4.y;
            Ws[kf * 4 + 2][m] = w4.z; Ws[kf * 4 + 3][m] = w4.w;
        }
        __syncthreads();
#pragma unroll
        for (int k = 0; k < 32; ++k) {
            float av[4], bv[4];
#pragma unroll
            for (int i = 0; i < 4; ++i) av[i] = As[k][ty * 4 + i];
#pragma unroll
            for (int j = 0; j < 4; ++j) bv[j] = Ws[k][tx * 4 + j];
#pragma unroll
            for (int i = 0; i < 4; ++i)
#pragma unroll
                for (int j = 0; j < 4; ++j)
                    acc[i][j] = fmaf(av[i], bv[j], acc[i][j]);
        }
        __syncthreads();
    }
#pragma unroll
    for (int i = 0; i < 4; ++i)
#pragma unroll
        for (int j = 0; j < 4; ++j) {
            size_t off = (size_t)(mBase + ty * 4 + i) * N + nBase + tx * 4 + j;
            if (ACCUM) C[off] += acc[i][j];
            else       C[off] = acc[i][j];
        }
}

// ---------------- causal depthwise conv (K=8) + SiLU ----------------
__global__ void k_conv_silu(const float* __restrict__ xz,
                            const float* __restrict__ cw,
                            const float* __restrict__ cb,
                            float* __restrict__ xc) {
    int tid = blockIdx.x * blockDim.x + threadIdx.x;   // BB*LL*DI
    int e = tid & (DI - 1);
    int l = (tid >> 8) & (LL - 1);
    int b = tid >> 19;
    float acc = cb[e];
#pragma unroll
    for (int k = 0; k < KC; ++k) {
        int pos = l + k - (KC - 1);
        float v = (pos >= 0) ? xz[((size_t)(b * LL + pos) << 9) + e] : 0.f;
        acc = fmaf(v, cw[e * KC + k], acc);
    }
    xc[tid] = acc / (1.f + __expf(-acc));
}

// ---------------- wave-parallel W_x projection + delta = softplus(dt@W_dt + b_dt) ----------------
__global__ __launch_bounds__(256) void k_wx_delta(const float* __restrict__ xc,
                                                  const float* __restrict__ Wx,
                                                  const float* __restrict__ Wdt,
                                                  const float* __restrict__ bdt,
                                                  float* __restrict__ BC,
                                                  float* __restrict__ delta) {
    int lane = threadIdx.x & 63;
    int t = blockIdx.x * 4 + (threadIdx.x >> 6);
    const float* xr = &xc[(size_t)t * DI];
    float x0 = xr[lane], x1 = xr[lane + 64], x2 = xr[lane + 128], x3 = xr[lane + 192];
    float dt[8];
    float bcv = 0.f;
#pragma unroll
    for (int o = 0; o < 40; ++o) {
        const float* w = &Wx[o * DI];
        float s = x0 * w[lane];
        s = fmaf(x1, w[lane + 64], s);
        s = fmaf(x2, w[lane + 128], s);
        s = fmaf(x3, w[lane + 192], s);
#pragma unroll
        for (int off = 32; off; off >>= 1) s += __shfl_xor(s, off);
        if (o < 8) dt[o] = s;
        else if (lane == o - 8) bcv = s;
    }
    if (lane < 32) BC[(size_t)t * 32 + lane] = bcv;
#pragma unroll
    for (int j = 0; j < 4; ++j) {
        int e = lane + 64 * j;
        float s = bdt[e];
#pragma unroll
        for (int r = 0; r < 8; ++r) s = fmaf(dt[r], Wdt[e * 8 + r], s);
        delta[(size_t)t * DI + e] = fmaxf(s, 0.f) + log1pf(__expf(-fabsf(s)));
    }
}

// ---------------- scan phase 1: per-chunk decay product + local end state ----------------
// One thread per (b, c, e, 4n): 4 h-chains in registers, float4 B loads.
__global__ __launch_bounds__(256) void k_scan1(const float* __restrict__ delta,
                                               const float* __restrict__ xc,
                                               const float* __restrict__ BC,
                                               const float* __restrict__ A_log,
                                               float* __restrict__ P,
                                               float* __restrict__ hend) {
    int blk = blockIdx.x;              // BB*NC*4
    int eg = blk & 3;
    int c = (blk >> 2) & (NC - 1);
    int b = blk >> 8;
    int tid = threadIdx.x;
    int e = eg * 64 + (tid >> 2);
    int ng = tid & 3;                  // n = 4*ng..4*ng+3
    float4 al = *(const float4*)&A_log[e * DS + 4 * ng];
    float Aen[4] = {-__expf(al.x), -__expf(al.y), -__expf(al.z), -__expf(al.w)};
    float h[4] = {}, Pl[4] = {1.f, 1.f, 1.f, 1.f};
    int base = b * LL + c * CT;
    const float* dp = delta + (size_t)base * DI + e;
    const float* up = xc + (size_t)base * DI + e;
    const float* bp = BC + (size_t)base * 32 + 4 * ng;
    for (int l0 = 0; l0 < CT; l0 += SU) {
        float d[SU], u[SU];
        float4 bm[SU];
#pragma unroll
        for (int j = 0; j < SU; ++j) {
            d[j]  = dp[(l0 + j) * DI];
            u[j]  = up[(l0 + j) * DI];
            bm[j] = *(const float4*)&bp[(l0 + j) * 32];
        }
#pragma unroll
        for (int j = 0; j < SU; ++j) {
            float du = d[j] * u[j];
            float a0 = __expf(d[j] * Aen[0]);
            float a1 = __expf(d[j] * Aen[1]);
            float a2 = __expf(d[j] * Aen[2]);
            float a3 = __expf(d[j] * Aen[3]);
            h[0] = fmaf(h[0], a0, du * bm[j].x);
            h[1] = fmaf(h[1], a1, du * bm[j].y);
            h[2] = fmaf(h[2], a2, du * bm[j].z);
            h[3] = fmaf(h[3], a3, du * bm[j].w);
            Pl[0] *= a0; Pl[1] *= a1; Pl[2] *= a2; Pl[3] *= a3;
        }
    }
    size_t oidx = (((size_t)(b * NC + c)) * DI + e) * DS + 4 * ng;
    *(float4*)&P[oidx]    = make_float4(Pl[0], Pl[1], Pl[2], Pl[3]);
    *(float4*)&hend[oidx] = make_float4(h[0], h[1], h[2], h[3]);
}

// ---------------- scan phase 2: sequential carry over NC chunks ----------------
__global__ void k_scan_carry(const float* __restrict__ P,
                             const float* __restrict__ hend,
                             float* __restrict__ hin) {
    int tid = blockIdx.x * blockDim.x + threadIdx.x;   // BB*DI*DS = 16384
    int n = tid & 15;
    int e = (tid >> 4) & 255;
    int b = tid >> 12;
    float carry = 0.f;
    for (int c = 0; c < NC; ++c) {
        size_t idx = (((size_t)(b * NC + c)) * DI + e) * DS + n;
        hin[idx] = carry;
        carry = fmaf(P[idx], carry, hend[idx]);
    }
}

// ---------------- scan phase 3: full scan + fused gating ----------------
__global__ __launch_bounds__(256) void k_scan3(const float* __restrict__ delta,
                                               const float* __restrict__ xc,
                                               const float* __restrict__ BC,
                                               const float* __restrict__ A_log,
                                               const float* __restrict__ hin,
                                               const float* __restrict__ xz,
                                               const float* __restrict__ Dsk,
                                               float* __restrict__ y) {
    int blk = blockIdx.x;              // BB*NC*4
    int eg = blk & 3;
    int c = (blk >> 2) & (NC - 1);
    int b = blk >> 8;
    int tid = threadIdx.x;
    int e = eg * 64 + (tid >> 2);
    int ng = tid & 3;
    float4 al = *(const float4*)&A_log[e * DS + 4 * ng];
    float Aen[4] = {-__expf(al.x), -__expf(al.y), -__expf(al.z), -__expf(al.w)};
    float dsk = Dsk[e];
    size_t hidx = (((size_t)(b * NC + c)) * DI + e) * DS + 4 * ng;
    float4 h4 = *(const float4*)&hin[hidx];
    float h[4] = {h4.x, h4.y, h4.z, h4.w};
    int base = b * LL + c * CT;
    const float* dp = delta + (size_t)base * DI + e;
    const float* up = xc + (size_t)base * DI + e;
    const float* bp = BC + (size_t)base * 32 + 4 * ng;
    const float* zp = xz + ((size_t)base << 9) + DI + e;
    float* yp = y + (size_t)base * DI + e;
    for (int l0 = 0; l0 < CT; l0 += SU) {
        float d[SU], u[SU], zv[SU];
        float4 bm[SU], cm[SU];
#pragma unroll
        for (int j = 0; j < SU; ++j) {
            d[j]  = dp[(l0 + j) * DI];
            u[j]  = up[(l0 + j) * DI];
            bm[j] = *(const float4*)&bp[(l0 + j) * 32];
            cm[j] = *(const float4*)&bp[(l0 + j) * 32 + 16];
            zv[j] = zp[(size_t)(l0 + j) << 9];
        }
#pragma unroll
        for (int j = 0; j < SU; ++j) {
            float du = d[j] * u[j];
            float a0 = __expf(d[j] * Aen[0]);
            float a1 = __expf(d[j] * Aen[1]);
            float a2 = __expf(d[j] * Aen[2]);
            float a3 = __expf(d[j] * Aen[3]);
            h[0] = fmaf(h[0], a0, du * bm[j].x);
            h[1] = fmaf(h[1], a1, du * bm[j].y);
            h[2] = fmaf(h[2], a2, du * bm[j].z);
            h[3] = fmaf(h[3], a3, du * bm[j].w);
            float yc = h[0] * cm[j].x;
            yc = fmaf(h[1], cm[j].y, yc);
            yc = fmaf(h[2], cm[j].z, yc);
            yc = fmaf(h[3], cm[j].w, yc);
            yc += __shfl_xor(yc, 1);
            yc += __shfl_xor(yc, 2);
            if (ng == 0) {
                float z = zv[j];
                float val = (yc + dsk * u[j]) * (z / (1.f + __expf(-z)));
                yp[(l0 + j) * DI] = val;
            }
        }
    }
}

// ---------------- final projection: out[t] = h[t,:] . out_w + out_b ----------------
__global__ void k_out(const float* __restrict__ h,
                      const float* __restrict__ ow,
                      const float* __restrict__ ob,
                      float* __restrict__ out) {
    int t = blockIdx.x * 4 + (threadIdx.x >> 6);
    int lane = threadIdx.x & 63;
    float s = h[t * DM + lane] * ow[lane] + h[t * DM + lane + 64] * ow[lane + 64];
#pragma unroll
    for (int off = 32; off; off >>= 1) s += __shfl_xor(s, off);
    if (lane == 0) out[t] = s + ob[0];
}

extern "C" void kernel_launch(void* const* d_in, const int* in_sizes, int n_in,
                              void* d_out, int out_size, void* d_ws, size_t ws_size,
                              hipStream_t stream) {
    (void)in_sizes; (void)n_in; (void)out_size; (void)ws_size;
    const float* x      = (const float*)d_in[0];
    const float* pcw    = (const float*)d_in[1];
    const float* pcb    = (const float*)d_in[2];
    const float* ln_w   = (const float*)d_in[3];
    const float* ln_b   = (const float*)d_in[4];
    const float* W_in   = (const float*)d_in[5];
    const float* conv_w = (const float*)d_in[6];
    const float* conv_b = (const float*)d_in[7];
    const float* W_x    = (const float*)d_in[8];
    const float* W_dt   = (const float*)d_in[9];
    const float* b_dt   = (const float*)d_in[10];
    const float* A_log  = (const float*)d_in[11];
    const float* D_skip = (const float*)d_in[12];
    const float* W_out  = (const float*)d_in[13];
    const float* out_w  = (const float*)d_in[14];
    const float* out_b  = (const float*)d_in[15];

    float* ws    = (float*)d_ws;
    float* h     = ws;                              // BL*DM
    float* ln    = h     + (size_t)BL * DM;         // BL*DM
    float* xz    = ln    + (size_t)BL * DM;         // BL*512
    float* xc    = xz    + (size_t)BL * 2 * DI;     // BL*256
    float* BC    = xc    + (size_t)BL * DI;         // BL*32
    float* delta = BC    + (size_t)BL * 2 * DS;     // BL*256
    float* y     = delta + (size_t)BL * DI;         // BL*256
    float* P     = y     + (size_t)BL * DI;         // BB*NC*DI*DS
    float* hend  = P     + (size_t)BB * NC * DI * DS;
    float* hin   = hend  + (size_t)BB * NC * DI * DS;

    k_preconv_gelu<<<(BB * LL * DM) / 256, 256, 0, stream>>>(x, pcw, pcb, h);

    for (int blk = 0; blk < NB; ++blk) {
        k_layernorm<<<BL / 4, 256, 0, stream>>>(h, ln_w + blk * DM, ln_b + blk * DM, ln);
        k_gemm<2 * DI, DM, false><<<dim3(BL / 64, (2 * DI) / 64), 256, 0, stream>>>(
            ln, W_in + (size_t)blk * 2 * DI * DM, xz);
        k_conv_silu<<<(BL * DI) / 256, 256, 0, stream>>>(
            xz, conv_w + (size_t)blk * DI * KC, conv_b + blk * DI, xc);
        k_wx_delta<<<BL / 4, 256, 0, stream>>>(
            xc, W_x + (size_t)blk * 40 * DI, W_dt + (size_t)blk * DI * DTR,
            b_dt + blk * DI, BC, delta);
        k_scan1<<<BB * NC * 4, 256, 0, stream>>>(
            delta, xc, BC, A_log + (size_t)blk * DI * DS, P, hend);
        k_scan_carry<<<(BB * DI * DS) / 256, 256, 0, stream>>>(P, hend, hin);
        k_scan3<<<BB * NC * 4, 256, 0, stream>>>(
            delta, xc, BC, A_log + (size_t)blk * DI * DS, hin, xz,
            D_skip + blk * DI, y);
        k_gemm<DM, DI, true><<<dim3(BL / 64, DM / 64), 256, 0, stream>>>(
            y, W_out + (size_t)blk * DM * DI, h);
    }

    k_out<<<BL / 4, 256, 0, stream>>>(h, out_w, out_b, (float*)d_out);
}

// Round 5
// 742.209 us; speedup vs baseline: 1.5132x; 1.1637x over previous
//
#include <hip/hip_runtime.h>
#include <hip/hip_bf16.h>
#include <math.h>

#define BB 4
#define LL 2048
#define DM 128
#define DI 256
#define DS 16
#define DTR 8
#define NB 6
#define KPRE 7
#define KC 8
#define NC 64       // chunks per sequence
#define CT 32       // chunk length (NC*CT == LL)
#define BL (BB*LL)  // 8192 tokens
#define SU 4        // scan unroll factor

typedef __attribute__((ext_vector_type(8))) short short8v;
typedef __attribute__((ext_vector_type(4))) float f32x4;

// ---------------- pre-conv (K=7, pad 3/3) + exact GELU ----------------
__global__ void k_preconv_gelu(const float* __restrict__ x,
                               const float* __restrict__ w,
                               const float* __restrict__ bias,
                               float* __restrict__ h) {
    int tid = blockIdx.x * blockDim.x + threadIdx.x;   // BB*LL*DM
    int d = tid & (DM - 1);
    int l = (tid >> 7) & (LL - 1);
    int b = tid >> 18;
    float acc = bias[d];
#pragma unroll
    for (int k = 0; k < KPRE; ++k) {
        int pos = l + k - 3;
        float xv = (pos >= 0 && pos < LL) ? x[b * LL + pos] : 0.f;
        acc = fmaf(xv, w[d * KPRE + k], acc);
    }
    h[tid] = 0.5f * acc * (1.f + erff(acc * 0.70710678118654752f));
}

// ---------------- weight conversion to bf16 (once per launch) ----------------
__global__ void k_cvt_weights(const float* __restrict__ Wi, const float* __restrict__ Wo,
                              __hip_bfloat16* __restrict__ wi, __hip_bfloat16* __restrict__ wo) {
    int i = blockIdx.x * 256 + threadIdx.x;
    const int NI = NB * 2 * DI * DM;   // 393216
    const int NO = NB * DM * DI;       // 196608
    if (i < NI) wi[i] = __float2bfloat16(Wi[i]);
    if (i < NO) wo[i] = __float2bfloat16(Wo[i]);
}

// ---------------- layernorm -> bf16 output (one wave per token, 4/block) ----------------
__global__ __launch_bounds__(256) void k_layernorm(const float* __restrict__ h,
                            const float* __restrict__ w,
                            const float* __restrict__ b,
                            __hip_bfloat16* __restrict__ out) {
    int t = blockIdx.x * 4 + (threadIdx.x >> 6);
    int lane = threadIdx.x & 63;
    float v0 = h[t * DM + lane];
    float v1 = h[t * DM + lane + 64];
    float s = v0 + v1;
#pragma unroll
    for (int off = 32; off; off >>= 1) s += __shfl_xor(s, off);
    float mean = s * (1.f / 128.f);
    float d0 = v0 - mean, d1 = v1 - mean;
    float q = d0 * d0 + d1 * d1;
#pragma unroll
    for (int off = 32; off; off >>= 1) q += __shfl_xor(q, off);
    float rstd = rsqrtf(q * (1.f / 128.f) + 1e-5f);
    out[t * DM + lane]      = __float2bfloat16(d0 * rstd * w[lane]      + b[lane]);
    out[t * DM + lane + 64] = __float2bfloat16(d1 * rstd * w[lane + 64] + b[lane + 64]);
}

// ---------------- bf16 MFMA GEMM: C[M x N] (+)= A[M x K] * W[N x K]^T ----------------
// 4 waves/block, each wave owns a 64x64 tile (4x4 fragments of 16x16x32 MFMA).
// Fragments loaded directly from global (contiguous 8 bf16 along K per lane).
template <int N, int K, bool ACCUM>
__global__ __launch_bounds__(256) void k_gemm_mfma(const __hip_bfloat16* __restrict__ A,
                                                   const __hip_bfloat16* __restrict__ W,
                                                   float* __restrict__ C) {
    int wave = threadIdx.x >> 6;         // 0..3
    int lane = threadIdx.x & 63;
    int wm = wave & 1, wn = wave >> 1;   // 2x2 wave grid
    int mBase = blockIdx.x * 128 + wm * 64;
    int nBase = blockIdx.y * 128 + wn * 64;
    int r  = lane & 15;                  // fragment row (A) / col (B)
    int kh = lane >> 4;                  // k-subgroup (0..3), k-offset = kh*8
    f32x4 acc[4][4] = {};
    for (int k0 = 0; k0 < K; k0 += 32) {
        short8v af[4], bf[4];
#pragma unroll
        for (int i = 0; i < 4; ++i) {
            af[i] = *(const short8v*)&A[(size_t)(mBase + i * 16 + r) * K + k0 + kh * 8];
            bf[i] = *(const short8v*)&W[(size_t)(nBase + i * 16 + r) * K + k0 + kh * 8];
        }
#pragma unroll
        for (int i = 0; i < 4; ++i)
#pragma unroll
            for (int j = 0; j < 4; ++j)
                acc[i][j] = __builtin_amdgcn_mfma_f32_16x16x32_bf16(af[i], bf[j], acc[i][j], 0, 0, 0);
    }
    // C/D layout (m89-verified): col = lane&15, row = (lane>>4)*4 + reg
#pragma unroll
    for (int i = 0; i < 4; ++i)
#pragma unroll
        for (int j = 0; j < 4; ++j)
#pragma unroll
            for (int rg = 0; rg < 4; ++rg) {
                size_t off = (size_t)(mBase + i * 16 + kh * 4 + rg) * N + nBase + j * 16 + r;
                if (ACCUM) C[off] += acc[i][j][rg];
                else       C[off] = acc[i][j][rg];
            }
}

// ---------------- causal depthwise conv (K=8) + SiLU ----------------
__global__ void k_conv_silu(const float* __restrict__ xz,
                            const float* __restrict__ cw,
                            const float* __restrict__ cb,
                            float* __restrict__ xc) {
    int tid = blockIdx.x * blockDim.x + threadIdx.x;   // BB*LL*DI
    int e = tid & (DI - 1);
    int l = (tid >> 8) & (LL - 1);
    int b = tid >> 19;
    float acc = cb[e];
#pragma unroll
    for (int k = 0; k < KC; ++k) {
        int pos = l + k - (KC - 1);
        float v = (pos >= 0) ? xz[((size_t)(b * LL + pos) << 9) + e] : 0.f;
        acc = fmaf(v, cw[e * KC + k], acc);
    }
    xc[tid] = acc / (1.f + __expf(-acc));
}

// ---------------- wave-parallel W_x projection + delta ----------------
__global__ __launch_bounds__(256) void k_wx_delta(const float* __restrict__ xc,
                                                  const float* __restrict__ Wx,
                                                  const float* __restrict__ Wdt,
                                                  const float* __restrict__ bdt,
                                                  float* __restrict__ BC,
                                                  float* __restrict__ delta) {
    int lane = threadIdx.x & 63;
    int t = blockIdx.x * 4 + (threadIdx.x >> 6);
    const float* xr = &xc[(size_t)t * DI];
    float x0 = xr[lane], x1 = xr[lane + 64], x2 = xr[lane + 128], x3 = xr[lane + 192];
    float dt[8];
    float bcv = 0.f;
#pragma unroll
    for (int o = 0; o < 40; ++o) {
        const float* w = &Wx[o * DI];
        float s = x0 * w[lane];
        s = fmaf(x1, w[lane + 64], s);
        s = fmaf(x2, w[lane + 128], s);
        s = fmaf(x3, w[lane + 192], s);
#pragma unroll
        for (int off = 32; off; off >>= 1) s += __shfl_xor(s, off);
        if (o < 8) dt[o] = s;
        else if (lane == o - 8) bcv = s;
    }
    if (lane < 32) BC[(size_t)t * 32 + lane] = bcv;
#pragma unroll
    for (int j = 0; j < 4; ++j) {
        int e = lane + 64 * j;
        float s = bdt[e];
#pragma unroll
        for (int r = 0; r < 8; ++r) s = fmaf(dt[r], Wdt[e * 8 + r], s);
        delta[(size_t)t * DI + e] = fmaxf(s, 0.f) + log1pf(__expf(-fabsf(s)));
    }
}

// ---------------- scan phase 1 ----------------
__global__ __launch_bounds__(256) void k_scan1(const float* __restrict__ delta,
                                               const float* __restrict__ xc,
                                               const float* __restrict__ BC,
                                               const float* __restrict__ A_log,
                                               float* __restrict__ P,
                                               float* __restrict__ hend) {
    int blk = blockIdx.x;              // BB*NC*4
    int eg = blk & 3;
    int c = (blk >> 2) & (NC - 1);
    int b = blk >> 8;
    int tid = threadIdx.x;
    int e = eg * 64 + (tid >> 2);
    int ng = tid & 3;                  // n = 4*ng..4*ng+3
    float4 al = *(const float4*)&A_log[e * DS + 4 * ng];
    float Aen[4] = {-__expf(al.x), -__expf(al.y), -__expf(al.z), -__expf(al.w)};
    float h[4] = {}, Pl[4] = {1.f, 1.f, 1.f, 1.f};
    int base = b * LL + c * CT;
    const float* dp = delta + (size_t)base * DI + e;
    const float* up = xc + (size_t)base * DI + e;
    const float* bp = BC + (size_t)base * 32 + 4 * ng;
    for (int l0 = 0; l0 < CT; l0 += SU) {
        float d[SU], u[SU];
        float4 bm[SU];
#pragma unroll
        for (int j = 0; j < SU; ++j) {
            d[j]  = dp[(l0 + j) * DI];
            u[j]  = up[(l0 + j) * DI];
            bm[j] = *(const float4*)&bp[(l0 + j) * 32];
        }
#pragma unroll
        for (int j = 0; j < SU; ++j) {
            float du = d[j] * u[j];
            float a0 = __expf(d[j] * Aen[0]);
            float a1 = __expf(d[j] * Aen[1]);
            float a2 = __expf(d[j] * Aen[2]);
            float a3 = __expf(d[j] * Aen[3]);
            h[0] = fmaf(h[0], a0, du * bm[j].x);
            h[1] = fmaf(h[1], a1, du * bm[j].y);
            h[2] = fmaf(h[2], a2, du * bm[j].z);
            h[3] = fmaf(h[3], a3, du * bm[j].w);
            Pl[0] *= a0; Pl[1] *= a1; Pl[2] *= a2; Pl[3] *= a3;
        }
    }
    size_t oidx = (((size_t)(b * NC + c)) * DI + e) * DS + 4 * ng;
    *(float4*)&P[oidx]    = make_float4(Pl[0], Pl[1], Pl[2], Pl[3]);
    *(float4*)&hend[oidx] = make_float4(h[0], h[1], h[2], h[3]);
}

// ---------------- scan phase 2: carry ----------------
__global__ void k_scan_carry(const float* __restrict__ P,
                             const float* __restrict__ hend,
                             float* __restrict__ hin) {
    int tid = blockIdx.x * blockDim.x + threadIdx.x;   // BB*DI*DS = 16384
    int n = tid & 15;
    int e = (tid >> 4) & 255;
    int b = tid >> 12;
    float carry = 0.f;
    for (int c = 0; c < NC; ++c) {
        size_t idx = (((size_t)(b * NC + c)) * DI + e) * DS + n;
        hin[idx] = carry;
        carry = fmaf(P[idx], carry, hend[idx]);
    }
}

// ---------------- scan phase 3: full scan + fused gating -> bf16 y ----------------
__global__ __launch_bounds__(256) void k_scan3(const float* __restrict__ delta,
                                               const float* __restrict__ xc,
                                               const float* __restrict__ BC,
                                               const float* __restrict__ A_log,
                                               const float* __restrict__ hin,
                                               const float* __restrict__ xz,
                                               const float* __restrict__ Dsk,
                                               __hip_bfloat16* __restrict__ y) {
    int blk = blockIdx.x;              // BB*NC*4
    int eg = blk & 3;
    int c = (blk >> 2) & (NC - 1);
    int b = blk >> 8;
    int tid = threadIdx.x;
    int e = eg * 64 + (tid >> 2);
    int ng = tid & 3;
    float4 al = *(const float4*)&A_log[e * DS + 4 * ng];
    float Aen[4] = {-__expf(al.x), -__expf(al.y), -__expf(al.z), -__expf(al.w)};
    float dsk = Dsk[e];
    size_t hidx = (((size_t)(b * NC + c)) * DI + e) * DS + 4 * ng;
    float4 h4 = *(const float4*)&hin[hidx];
    float h[4] = {h4.x, h4.y, h4.z, h4.w};
    int base = b * LL + c * CT;
    const float* dp = delta + (size_t)base * DI + e;
    const float* up = xc + (size_t)base * DI + e;
    const float* bp = BC + (size_t)base * 32 + 4 * ng;
    const float* zp = xz + ((size_t)base << 9) + DI + e;
    __hip_bfloat16* yp = y + (size_t)base * DI + e;
    for (int l0 = 0; l0 < CT; l0 += SU) {
        float d[SU], u[SU], zv[SU];
        float4 bm[SU], cm[SU];
#pragma unroll
        for (int j = 0; j < SU; ++j) {
            d[j]  = dp[(l0 + j) * DI];
            u[j]  = up[(l0 + j) * DI];
            bm[j] = *(const float4*)&bp[(l0 + j) * 32];
            cm[j] = *(const float4*)&bp[(l0 + j) * 32 + 16];
            zv[j] = zp[(size_t)(l0 + j) << 9];
        }
#pragma unroll
        for (int j = 0; j < SU; ++j) {
            float du = d[j] * u[j];
            float a0 = __expf(d[j] * Aen[0]);
            float a1 = __expf(d[j] * Aen[1]);
            float a2 = __expf(d[j] * Aen[2]);
            float a3 = __expf(d[j] * Aen[3]);
            h[0] = fmaf(h[0], a0, du * bm[j].x);
            h[1] = fmaf(h[1], a1, du * bm[j].y);
            h[2] = fmaf(h[2], a2, du * bm[j].z);
            h[3] = fmaf(h[3], a3, du * bm[j].w);
            float yc = h[0] * cm[j].x;
            yc = fmaf(h[1], cm[j].y, yc);
            yc = fmaf(h[2], cm[j].z, yc);
            yc = fmaf(h[3], cm[j].w, yc);
            yc += __shfl_xor(yc, 1);
            yc += __shfl_xor(yc, 2);
            if (ng == 0) {
                float z = zv[j];
                float val = (yc + dsk * u[j]) * (z / (1.f + __expf(-z)));
                yp[(l0 + j) * DI] = __float2bfloat16(val);
            }
        }
    }
}

// ---------------- final projection ----------------
__global__ void k_out(const float* __restrict__ h,
                      const float* __restrict__ ow,
                      const float* __restrict__ ob,
                      float* __restrict__ out) {
    int t = blockIdx.x * 4 + (threadIdx.x >> 6);
    int lane = threadIdx.x & 63;
    float s = h[t * DM + lane] * ow[lane] + h[t * DM + lane + 64] * ow[lane + 64];
#pragma unroll
    for (int off = 32; off; off >>= 1) s += __shfl_xor(s, off);
    if (lane == 0) out[t] = s + ob[0];
}

extern "C" void kernel_launch(void* const* d_in, const int* in_sizes, int n_in,
                              void* d_out, int out_size, void* d_ws, size_t ws_size,
                              hipStream_t stream) {
    (void)in_sizes; (void)n_in; (void)out_size; (void)ws_size;
    const float* x      = (const float*)d_in[0];
    const float* pcw    = (const float*)d_in[1];
    const float* pcb    = (const float*)d_in[2];
    const float* ln_w   = (const float*)d_in[3];
    const float* ln_b   = (const float*)d_in[4];
    const float* W_in   = (const float*)d_in[5];
    const float* conv_w = (const float*)d_in[6];
    const float* conv_b = (const float*)d_in[7];
    const float* W_x    = (const float*)d_in[8];
    const float* W_dt   = (const float*)d_in[9];
    const float* b_dt   = (const float*)d_in[10];
    const float* A_log  = (const float*)d_in[11];
    const float* D_skip = (const float*)d_in[12];
    const float* W_out  = (const float*)d_in[13];
    const float* out_w  = (const float*)d_in[14];
    const float* out_b  = (const float*)d_in[15];

    float* ws    = (float*)d_ws;
    float* h     = ws;                              // BL*DM
    float* xz    = h     + (size_t)BL * DM;         // BL*512
    float* xc    = xz    + (size_t)BL * 2 * DI;     // BL*256
    float* BC    = xc    + (size_t)BL * DI;         // BL*32
    float* delta = BC    + (size_t)BL * 2 * DS;     // BL*256
    float* P     = delta + (size_t)BL * DI;         // BB*NC*DI*DS
    float* hend  = P     + (size_t)BB * NC * DI * DS;
    float* hin   = hend  + (size_t)BB * NC * DI * DS;
    __hip_bfloat16* ln_bf = (__hip_bfloat16*)(hin + (size_t)BB * NC * DI * DS);  // BL*DM
    __hip_bfloat16* y_bf  = ln_bf + (size_t)BL * DM;                             // BL*DI
    __hip_bfloat16* wi_bf = y_bf  + (size_t)BL * DI;                             // NB*512*128
    __hip_bfloat16* wo_bf = wi_bf + (size_t)NB * 2 * DI * DM;                    // NB*128*256

    k_preconv_gelu<<<(BB * LL * DM) / 256, 256, 0, stream>>>(x, pcw, pcb, h);
    k_cvt_weights<<<(NB * 2 * DI * DM) / 256, 256, 0, stream>>>(W_in, W_out, wi_bf, wo_bf);

    for (int blk = 0; blk < NB; ++blk) {
        k_layernorm<<<BL / 4, 256, 0, stream>>>(h, ln_w + blk * DM, ln_b + blk * DM, ln_bf);
        k_gemm_mfma<2 * DI, DM, false><<<dim3(BL / 128, (2 * DI) / 128), 256, 0, stream>>>(
            ln_bf, wi_bf + (size_t)blk * 2 * DI * DM, xz);
        k_conv_silu<<<(BL * DI) / 256, 256, 0, stream>>>(
            xz, conv_w + (size_t)blk * DI * KC, conv_b + blk * DI, xc);
        k_wx_delta<<<BL / 4, 256, 0, stream>>>(
            xc, W_x + (size_t)blk * 40 * DI, W_dt + (size_t)blk * DI * DTR,
            b_dt + blk * DI, BC, delta);
        k_scan1<<<BB * NC * 4, 256, 0, stream>>>(
            delta, xc, BC, A_log + (size_t)blk * DI * DS, P, hend);
        k_scan_carry<<<(BB * DI * DS) / 256, 256, 0, stream>>>(P, hend, hin);
        k_scan3<<<BB * NC * 4, 256, 0, stream>>>(
            delta, xc, BC, A_log + (size_t)blk * DI * DS, hin, xz,
            D_skip + blk * DI, y_bf);
        k_gemm_mfma<DM, DI, true><<<dim3(BL / 128, DM / 128), 256, 0, stream>>>(
            y_bf, wo_bf + (size_t)blk * DM * DI, h);
    }

    k_out<<<BL / 4, 256, 0, stream>>>(h, out_w, out_b, (float*)d_out);
}

// Round 6
// 686.898 us; speedup vs baseline: 1.6350x; 1.0805x over previous
//
#include <hip/hip_runtime.h>
#include <hip/hip_bf16.h>
#include <math.h>

#define BB 4
#define LL 2048
#define DM 128
#define DI 256
#define DS 16
#define DTR 8
#define NB 6
#define KPRE 7
#define KC 8
#define NC 64       // chunks per sequence
#define CT 32       // chunk length (NC*CT == LL)
#define BL (BB*LL)  // 8192 tokens
#define SU 4        // scan unroll factor

typedef __attribute__((ext_vector_type(8))) short short8v;
typedef __attribute__((ext_vector_type(4))) float f32x4;

// ---------------- pre-conv (K=7, pad 3/3) + exact GELU + fused weight cvt ----------------
__global__ void k_preconv_gelu(const float* __restrict__ x,
                               const float* __restrict__ w,
                               const float* __restrict__ bias,
                               float* __restrict__ h,
                               const float* __restrict__ Wi,
                               const float* __restrict__ Wo,
                               __hip_bfloat16* __restrict__ wi,
                               __hip_bfloat16* __restrict__ wo) {
    int tid = blockIdx.x * blockDim.x + threadIdx.x;   // BB*LL*DM = 1M
    int d = tid & (DM - 1);
    int l = (tid >> 7) & (LL - 1);
    int b = tid >> 18;
    float acc = bias[d];
#pragma unroll
    for (int k = 0; k < KPRE; ++k) {
        int pos = l + k - 3;
        float xv = (pos >= 0 && pos < LL) ? x[b * LL + pos] : 0.f;
        acc = fmaf(xv, w[d * KPRE + k], acc);
    }
    h[tid] = 0.5f * acc * (1.f + erff(acc * 0.70710678118654752f));
    // fused one-time weight conversion
    if (tid < NB * 2 * DI * DM) wi[tid] = __float2bfloat16(Wi[tid]);
    if (tid < NB * DM * DI)     wo[tid] = __float2bfloat16(Wo[tid]);
}

// ---------------- fused LayerNorm + bf16 MFMA GEMM1: xz[M x 512] = LN(h)[M x 128] * W[512 x 128]^T ----
// LN into swizzled bf16 LDS tile; MFMA A-fragments from LDS, B from global.
__global__ __launch_bounds__(256) void k_ln_gemm1(const float* __restrict__ h,
                                                  const float* __restrict__ lw,
                                                  const float* __restrict__ lb,
                                                  const __hip_bfloat16* __restrict__ W,
                                                  float* __restrict__ xz) {
    __shared__ __hip_bfloat16 As[128 * 128];   // 32 KB, XOR-swizzled
    int wave = threadIdx.x >> 6;
    int lane = threadIdx.x & 63;
    int mBase = blockIdx.x * 128;
    int nBase = blockIdx.y * 128;
    // ---- LN phase: 32 rows per wave ----
    for (int it = 0; it < 32; ++it) {
        int row = wave * 32 + it;
        int t = mBase + row;
        float v0 = h[t * DM + lane];
        float v1 = h[t * DM + lane + 64];
        float s = v0 + v1;
#pragma unroll
        for (int off = 32; off; off >>= 1) s += __shfl_xor(s, off);
        float mean = s * (1.f / 128.f);
        float d0 = v0 - mean, d1 = v1 - mean;
        float q = d0 * d0 + d1 * d1;
#pragma unroll
        for (int off = 32; off; off >>= 1) q += __shfl_xor(q, off);
        float rstd = rsqrtf(q * (1.f / 128.f) + 1e-5f);
        int sw = (row & 7) << 3;
        As[row * 128 + (lane ^ sw)]        = __float2bfloat16(d0 * rstd * lw[lane] + lb[lane]);
        As[row * 128 + ((lane + 64) ^ sw)] = __float2bfloat16(d1 * rstd * lw[lane + 64] + lb[lane + 64]);
    }
    __syncthreads();
    // ---- MFMA phase: 4 waves as 2x2, each 64x64 ----
    int wm = wave & 1, wn = wave >> 1;
    int r  = lane & 15;
    int kh = lane >> 4;
    f32x4 acc[4][4] = {};
    for (int k0 = 0; k0 < DM; k0 += 32) {
        short8v af[4], bf[4];
#pragma unroll
        for (int i = 0; i < 4; ++i) {
            int row = wm * 64 + i * 16 + r;
            int cbk = (k0 >> 3) + kh;                       // 8-elem column block
            af[i] = *(const short8v*)&As[row * 128 + ((cbk ^ (row & 7)) << 3)];
            bf[i] = *(const short8v*)&W[(size_t)(nBase + wn * 64 + i * 16 + r) * DM + k0 + kh * 8];
        }
#pragma unroll
        for (int i = 0; i < 4; ++i)
#pragma unroll
            for (int j = 0; j < 4; ++j)
                acc[i][j] = __builtin_amdgcn_mfma_f32_16x16x32_bf16(af[i], bf[j], acc[i][j], 0, 0, 0);
    }
#pragma unroll
    for (int i = 0; i < 4; ++i)
#pragma unroll
        for (int j = 0; j < 4; ++j)
#pragma unroll
            for (int rg = 0; rg < 4; ++rg) {
                size_t off = (size_t)(mBase + wm * 64 + i * 16 + kh * 4 + rg) * (2 * DI)
                           + nBase + wn * 64 + j * 16 + r;
                xz[off] = acc[i][j][rg];
            }
}

// ---------------- bf16 MFMA GEMM2: h[M x 128] += y[M x 256] * W[128 x 256]^T ----------------
__global__ __launch_bounds__(256) void k_gemm2_mfma(const __hip_bfloat16* __restrict__ A,
                                                    const __hip_bfloat16* __restrict__ W,
                                                    float* __restrict__ C) {
    int wave = threadIdx.x >> 6;
    int lane = threadIdx.x & 63;
    int wm = wave & 1, wn = wave >> 1;
    int mBase = blockIdx.x * 128 + wm * 64;
    int nBase = wn * 64;
    int r  = lane & 15;
    int kh = lane >> 4;
    f32x4 acc[4][4] = {};
    for (int k0 = 0; k0 < DI; k0 += 32) {
        short8v af[4], bf[4];
#pragma unroll
        for (int i = 0; i < 4; ++i) {
            af[i] = *(const short8v*)&A[(size_t)(mBase + i * 16 + r) * DI + k0 + kh * 8];
            bf[i] = *(const short8v*)&W[(size_t)(nBase + i * 16 + r) * DI + k0 + kh * 8];
        }
#pragma unroll
        for (int i = 0; i < 4; ++i)
#pragma unroll
            for (int j = 0; j < 4; ++j)
                acc[i][j] = __builtin_amdgcn_mfma_f32_16x16x32_bf16(af[i], bf[j], acc[i][j], 0, 0, 0);
    }
#pragma unroll
    for (int i = 0; i < 4; ++i)
#pragma unroll
        for (int j = 0; j < 4; ++j)
#pragma unroll
            for (int rg = 0; rg < 4; ++rg) {
                size_t off = (size_t)(mBase + i * 16 + kh * 4 + rg) * DM + nBase + j * 16 + r;
                C[off] += acc[i][j][rg];
            }
}

// ---------------- fused depthwise conv + SiLU + W_x projection + delta ----------------
// One wave per token; each lane owns channels lane, lane+64, lane+128, lane+192.
__global__ __launch_bounds__(256) void k_conv_wx(const float* __restrict__ xz,
                                                 const float* __restrict__ cw,
                                                 const float* __restrict__ cbs,
                                                 const float* __restrict__ Wx,
                                                 const float* __restrict__ Wdt,
                                                 const float* __restrict__ bdt,
                                                 float* __restrict__ xc,
                                                 float* __restrict__ BC,
                                                 float* __restrict__ delta) {
    int lane = threadIdx.x & 63;
    int t = blockIdx.x * 4 + (threadIdx.x >> 6);
    int tl = t & (LL - 1);
    int b = t >> 11;
    float xv[4];
#pragma unroll
    for (int j = 0; j < 4; ++j) {
        int e = lane + 64 * j;
        float4 cw0 = *(const float4*)&cw[e * KC];
        float4 cw1 = *(const float4*)&cw[e * KC + 4];
        float wts[8] = {cw0.x, cw0.y, cw0.z, cw0.w, cw1.x, cw1.y, cw1.z, cw1.w};
        float acc = cbs[e];
#pragma unroll
        for (int k = 0; k < KC; ++k) {
            int pos = tl + k - (KC - 1);
            float v = (pos >= 0) ? xz[((size_t)(b * LL + pos) << 9) + e] : 0.f;
            acc = fmaf(v, wts[k], acc);
        }
        xv[j] = acc / (1.f + __expf(-acc));
        xc[((size_t)t << 8) + e] = xv[j];
    }
    float dt[8];
    float bcv = 0.f;
#pragma unroll
    for (int o = 0; o < 40; ++o) {
        const float* w = &Wx[o * DI];
        float s = xv[0] * w[lane];
        s = fmaf(xv[1], w[lane + 64], s);
        s = fmaf(xv[2], w[lane + 128], s);
        s = fmaf(xv[3], w[lane + 192], s);
#pragma unroll
        for (int off = 32; off; off >>= 1) s += __shfl_xor(s, off);
        if (o < 8) dt[o] = s;
        else if (lane == o - 8) bcv = s;
    }
    if (lane < 32) BC[((size_t)t << 5) + lane] = bcv;
#pragma unroll
    for (int j = 0; j < 4; ++j) {
        int e = lane + 64 * j;
        float s = bdt[e];
#pragma unroll
        for (int r = 0; r < 8; ++r) s = fmaf(dt[r], Wdt[e * 8 + r], s);
        delta[((size_t)t << 8) + e] = fmaxf(s, 0.f) + log1pf(__expf(-fabsf(s)));
    }
}

// ---------------- scan phase 1 ----------------
__global__ __launch_bounds__(256) void k_scan1(const float* __restrict__ delta,
                                               const float* __restrict__ xc,
                                               const float* __restrict__ BC,
                                               const float* __restrict__ A_log,
                                               float* __restrict__ P,
                                               float* __restrict__ hend) {
    int blk = blockIdx.x;              // BB*NC*4
    int eg = blk & 3;
    int c = (blk >> 2) & (NC - 1);
    int b = blk >> 8;
    int tid = threadIdx.x;
    int e = eg * 64 + (tid >> 2);
    int ng = tid & 3;                  // n = 4*ng..4*ng+3
    float4 al = *(const float4*)&A_log[e * DS + 4 * ng];
    float Aen[4] = {-__expf(al.x), -__expf(al.y), -__expf(al.z), -__expf(al.w)};
    float h[4] = {}, Pl[4] = {1.f, 1.f, 1.f, 1.f};
    int base = b * LL + c * CT;
    const float* dp = delta + (size_t)base * DI + e;
    const float* up = xc + (size_t)base * DI + e;
    const float* bp = BC + (size_t)base * 32 + 4 * ng;
    for (int l0 = 0; l0 < CT; l0 += SU) {
        float d[SU], u[SU];
        float4 bm[SU];
#pragma unroll
        for (int j = 0; j < SU; ++j) {
            d[j]  = dp[(l0 + j) * DI];
            u[j]  = up[(l0 + j) * DI];
            bm[j] = *(const float4*)&bp[(l0 + j) * 32];
        }
#pragma unroll
        for (int j = 0; j < SU; ++j) {
            float du = d[j] * u[j];
            float a0 = __expf(d[j] * Aen[0]);
            float a1 = __expf(d[j] * Aen[1]);
            float a2 = __expf(d[j] * Aen[2]);
            float a3 = __expf(d[j] * Aen[3]);
            h[0] = fmaf(h[0], a0, du * bm[j].x);
            h[1] = fmaf(h[1], a1, du * bm[j].y);
            h[2] = fmaf(h[2], a2, du * bm[j].z);
            h[3] = fmaf(h[3], a3, du * bm[j].w);
            Pl[0] *= a0; Pl[1] *= a1; Pl[2] *= a2; Pl[3] *= a3;
        }
    }
    size_t oidx = (((size_t)(b * NC + c)) * DI + e) * DS + 4 * ng;
    *(float4*)&P[oidx]    = make_float4(Pl[0], Pl[1], Pl[2], Pl[3]);
    *(float4*)&hend[oidx] = make_float4(h[0], h[1], h[2], h[3]);
}

// ---------------- scan phase 2: carry ----------------
__global__ void k_scan_carry(const float* __restrict__ P,
                             const float* __restrict__ hend,
                             float* __restrict__ hin) {
    int tid = blockIdx.x * blockDim.x + threadIdx.x;   // BB*DI*DS = 16384
    int n = tid & 15;
    int e = (tid >> 4) & 255;
    int b = tid >> 12;
    float carry = 0.f;
    for (int c = 0; c < NC; ++c) {
        size_t idx = (((size_t)(b * NC + c)) * DI + e) * DS + n;
        hin[idx] = carry;
        carry = fmaf(P[idx], carry, hend[idx]);
    }
}

// ---------------- scan phase 3: full scan + fused gating -> bf16 y ----------------
__global__ __launch_bounds__(256) void k_scan3(const float* __restrict__ delta,
                                               const float* __restrict__ xc,
                                               const float* __restrict__ BC,
                                               const float* __restrict__ A_log,
                                               const float* __restrict__ hin,
                                               const float* __restrict__ xz,
                                               const float* __restrict__ Dsk,
                                               __hip_bfloat16* __restrict__ y) {
    int blk = blockIdx.x;              // BB*NC*4
    int eg = blk & 3;
    int c = (blk >> 2) & (NC - 1);
    int b = blk >> 8;
    int tid = threadIdx.x;
    int e = eg * 64 + (tid >> 2);
    int ng = tid & 3;
    float4 al = *(const float4*)&A_log[e * DS + 4 * ng];
    float Aen[4] = {-__expf(al.x), -__expf(al.y), -__expf(al.z), -__expf(al.w)};
    float dsk = Dsk[e];
    size_t hidx = (((size_t)(b * NC + c)) * DI + e) * DS + 4 * ng;
    float4 h4 = *(const float4*)&hin[hidx];
    float h[4] = {h4.x, h4.y, h4.z, h4.w};
    int base = b * LL + c * CT;
    const float* dp = delta + (size_t)base * DI + e;
    const float* up = xc + (size_t)base * DI + e;
    const float* bp = BC + (size_t)base * 32 + 4 * ng;
    const float* zp = xz + ((size_t)base << 9) + DI + e;
    __hip_bfloat16* yp = y + (size_t)base * DI + e;
    for (int l0 = 0; l0 < CT; l0 += SU) {
        float d[SU], u[SU], zv[SU];
        float4 bm[SU], cm[SU];
#pragma unroll
        for (int j = 0; j < SU; ++j) {
            d[j]  = dp[(l0 + j) * DI];
            u[j]  = up[(l0 + j) * DI];
            bm[j] = *(const float4*)&bp[(l0 + j) * 32];
            cm[j] = *(const float4*)&bp[(l0 + j) * 32 + 16];
            zv[j] = zp[(size_t)(l0 + j) << 9];
        }
#pragma unroll
        for (int j = 0; j < SU; ++j) {
            float du = d[j] * u[j];
            float a0 = __expf(d[j] * Aen[0]);
            float a1 = __expf(d[j] * Aen[1]);
            float a2 = __expf(d[j] * Aen[2]);
            float a3 = __expf(d[j] * Aen[3]);
            h[0] = fmaf(h[0], a0, du * bm[j].x);
            h[1] = fmaf(h[1], a1, du * bm[j].y);
            h[2] = fmaf(h[2], a2, du * bm[j].z);
            h[3] = fmaf(h[3], a3, du * bm[j].w);
            float yc = h[0] * cm[j].x;
            yc = fmaf(h[1], cm[j].y, yc);
            yc = fmaf(h[2], cm[j].z, yc);
            yc = fmaf(h[3], cm[j].w, yc);
            yc += __shfl_xor(yc, 1);
            yc += __shfl_xor(yc, 2);
            if (ng == 0) {
                float z = zv[j];
                float val = (yc + dsk * u[j]) * (z / (1.f + __expf(-z)));
                yp[(l0 + j) * DI] = __float2bfloat16(val);
            }
        }
    }
}

// ---------------- final projection ----------------
__global__ void k_out(const float* __restrict__ h,
                      const float* __restrict__ ow,
                      const float* __restrict__ ob,
                      float* __restrict__ out) {
    int t = blockIdx.x * 4 + (threadIdx.x >> 6);
    int lane = threadIdx.x & 63;
    float s = h[t * DM + lane] * ow[lane] + h[t * DM + lane + 64] * ow[lane + 64];
#pragma unroll
    for (int off = 32; off; off >>= 1) s += __shfl_xor(s, off);
    if (lane == 0) out[t] = s + ob[0];
}

extern "C" void kernel_launch(void* const* d_in, const int* in_sizes, int n_in,
                              void* d_out, int out_size, void* d_ws, size_t ws_size,
                              hipStream_t stream) {
    (void)in_sizes; (void)n_in; (void)out_size; (void)ws_size;
    const float* x      = (const float*)d_in[0];
    const float* pcw    = (const float*)d_in[1];
    const float* pcb    = (const float*)d_in[2];
    const float* ln_w   = (const float*)d_in[3];
    const float* ln_b   = (const float*)d_in[4];
    const float* W_in   = (const float*)d_in[5];
    const float* conv_w = (const float*)d_in[6];
    const float* conv_b = (const float*)d_in[7];
    const float* W_x    = (const float*)d_in[8];
    const float* W_dt   = (const float*)d_in[9];
    const float* b_dt   = (const float*)d_in[10];
    const float* A_log  = (const float*)d_in[11];
    const float* D_skip = (const float*)d_in[12];
    const float* W_out  = (const float*)d_in[13];
    const float* out_w  = (const float*)d_in[14];
    const float* out_b  = (const float*)d_in[15];

    float* ws    = (float*)d_ws;
    float* h     = ws;                              // BL*DM
    float* xz    = h     + (size_t)BL * DM;         // BL*512
    float* xc    = xz    + (size_t)BL * 2 * DI;     // BL*256
    float* BC    = xc    + (size_t)BL * DI;         // BL*32
    float* delta = BC    + (size_t)BL * 2 * DS;     // BL*256
    float* P     = delta + (size_t)BL * DI;         // BB*NC*DI*DS
    float* hend  = P     + (size_t)BB * NC * DI * DS;
    float* hin   = hend  + (size_t)BB * NC * DI * DS;
    __hip_bfloat16* y_bf  = (__hip_bfloat16*)(hin + (size_t)BB * NC * DI * DS);  // BL*DI
    __hip_bfloat16* wi_bf = y_bf  + (size_t)BL * DI;                             // NB*512*128
    __hip_bfloat16* wo_bf = wi_bf + (size_t)NB * 2 * DI * DM;                    // NB*128*256

    k_preconv_gelu<<<(BB * LL * DM) / 256, 256, 0, stream>>>(
        x, pcw, pcb, h, W_in, W_out, wi_bf, wo_bf);

    for (int blk = 0; blk < NB; ++blk) {
        k_ln_gemm1<<<dim3(BL / 128, (2 * DI) / 128), 256, 0, stream>>>(
            h, ln_w + blk * DM, ln_b + blk * DM, wi_bf + (size_t)blk * 2 * DI * DM, xz);
        k_conv_wx<<<BL / 4, 256, 0, stream>>>(
            xz, conv_w + (size_t)blk * DI * KC, conv_b + blk * DI,
            W_x + (size_t)blk * 40 * DI, W_dt + (size_t)blk * DI * DTR,
            b_dt + blk * DI, xc, BC, delta);
        k_scan1<<<BB * NC * 4, 256, 0, stream>>>(
            delta, xc, BC, A_log + (size_t)blk * DI * DS, P, hend);
        k_scan_carry<<<(BB * DI * DS) / 256, 256, 0, stream>>>(P, hend, hin);
        k_scan3<<<BB * NC * 4, 256, 0, stream>>>(
            delta, xc, BC, A_log + (size_t)blk * DI * DS, hin, xz,
            D_skip + blk * DI, y_bf);
        k_gemm2_mfma<<<BL / 128, 256, 0, stream>>>(
            y_bf, wo_bf + (size_t)blk * DM * DI, h);
    }

    k_out<<<BL / 4, 256, 0, stream>>>(h, out_w, out_b, (float*)d_out);
}